// Round 2
// baseline (3511.062 us; speedup 1.0000x reference)
//
#include <hip/hip_runtime.h>
#include <hip/hip_bf16.h>
#include <cstdint>
#include <cstddef>

#define NUM_USERS 100000
#define NUM_ITEMS 50000
#define NUM_NODES 150000
#define NUM_EDGES 2000000
#define BATCH 16384

// ---- monotone float<->uint key for atomicMax on floats (zero-init == -inf) ----
__device__ __forceinline__ unsigned f2key(float f) {
  unsigned u = __float_as_uint(f);
  return (u & 0x80000000u) ? ~u : (u | 0x80000000u);
}
__device__ __forceinline__ float key2f(unsigned k) {
  unsigned u = (k & 0x80000000u) ? (k & 0x7fffffffu) : ~k;
  return __uint_as_float(u);
}

// ---------------- init (no hipMemsetAsync anywhere) ----------------
__global__ void zero_kernel(int* __restrict__ count, unsigned* __restrict__ gkeys) {
  int i = blockIdx.x * blockDim.x + threadIdx.x;
  if (i < NUM_NODES) count[i] = 0;
  if (i < 2) gkeys[i] = 0u;
}

// ---------------- CSR construction ----------------
__global__ void hist_kernel(const int* __restrict__ dst, int* __restrict__ count) {
  int e = blockIdx.x * blockDim.x + threadIdx.x;
  if (e < NUM_EDGES) atomicAdd(&count[dst[e]], 1);
}

__global__ void scan_kernel(const int* __restrict__ count, int* __restrict__ offsets,
                            int* __restrict__ cursor) {
  __shared__ int ssum[1024];
  const int n = NUM_NODES;
  int t = threadIdx.x;
  const int chunk = (n + 1023) >> 10;
  int b = t * chunk;
  int e = b + chunk; if (e > n) e = n;
  if (b > n) b = n;
  int s = 0;
  for (int i = b; i < e; ++i) s += count[i];
  ssum[t] = s;
  __syncthreads();
  for (int off = 1; off < 1024; off <<= 1) {
    int v = 0;
    if (t >= off) v = ssum[t - off];
    __syncthreads();
    if (t >= off) ssum[t] += v;
    __syncthreads();
  }
  int run = (t == 0) ? 0 : ssum[t - 1];
  for (int i = b; i < e; ++i) {
    offsets[i] = run;
    cursor[i] = run;
    run += count[i];
  }
  if (t == 1023) offsets[n] = ssum[1023];  // == NUM_EDGES
}

__global__ void scatter_kernel(const int* __restrict__ src, const int* __restrict__ dst,
                               int* __restrict__ cursor, int* __restrict__ src_sorted) {
  int e = blockIdx.x * blockDim.x + threadIdx.x;
  if (e < NUM_EDGES) {
    int p = atomicAdd(&cursor[dst[e]], 1);
    src_sorted[p] = src[e];
  }
}

// ---------------- projected attention vectors: w1a[h][k] = sum_f W1[k, h*64+f]*a_l[h,f]
__global__ void proj1_kernel(const float* __restrict__ W1, const float* __restrict__ a1,
                             float* __restrict__ w1a, float* __restrict__ w1b) {
  int t = threadIdx.x;           // 256 threads: h = t>>6, k = t&63
  int h = t >> 6, k = t & 63;
  float sa = 0.f, sb = 0.f;
  for (int f = 0; f < 64; ++f) {
    float w = W1[(size_t)k * 256 + h * 64 + f];
    sa += w * a1[h * 128 + f];
    sb += w * a1[h * 128 + 64 + f];
  }
  w1a[h * 64 + k] = sa;
  w1b[h * 64 + k] = sb;
}

// ---------------- e1 tables straight from embeddings: e1s[n,h] = x_n . w1a[h] ----------------
__global__ __launch_bounds__(256) void e1_kernel(
    const float* __restrict__ ut, const float* __restrict__ it,
    const float* __restrict__ w1a, const float* __restrict__ w1b,
    float* __restrict__ e1s, float* __restrict__ e1d) {
  int wid = threadIdx.x >> 6, lane = threadIdx.x & 63;
  int node = blockIdx.x * 4 + wid;
  if (node >= NUM_NODES) return;
  const float* x = (node < NUM_USERS) ? ut + (size_t)node * 64
                                      : it + (size_t)(node - NUM_USERS) * 64;
  float xv = x[lane];
#pragma unroll
  for (int h = 0; h < 4; ++h) {
    float ps = xv * w1a[h * 64 + lane];
    float pd = xv * w1b[h * 64 + lane];
#pragma unroll
    for (int off = 32; off; off >>= 1) {
      ps += __shfl_xor(ps, off, 64);
      pd += __shfl_xor(pd, off, 64);
    }
    if (lane == 0) {
      e1s[(size_t)node * 4 + h] = ps;
      e1d[(size_t)node * 4 + h] = pd;
    }
  }
}

// ---------------- global max of leaky-relu attention logits ----------------
template <int HEADS>
__global__ __launch_bounds__(256) void maxatt_kernel(
    const int* __restrict__ src, const int* __restrict__ dst,
    const float* __restrict__ es, const float* __restrict__ ed,
    unsigned* __restrict__ gkey) {
  float m = -3.4e38f;
  int stride = gridDim.x * blockDim.x;
  for (int e = blockIdx.x * blockDim.x + threadIdx.x; e < NUM_EDGES; e += stride) {
    int s = src[e], d = dst[e];
#pragma unroll
    for (int h = 0; h < HEADS; ++h) {
      float v = es[(size_t)s * HEADS + h] + ed[(size_t)d * HEADS + h];
      v = v > 0.f ? v : 0.2f * v;
      m = fmaxf(m, v);
    }
  }
#pragma unroll
  for (int off = 32; off; off >>= 1) m = fmaxf(m, __shfl_xor(m, off, 64));
  if ((threadIdx.x & 63) == 0) atomicMax(gkey, f2key(m));
}

// ---------------- per-head GEMM1: h1h[150000 x 64] = all_emb @ W1[:, h*64:(h+1)*64] ----------------
__global__ __launch_bounds__(256) void gemm1_kernel(
    const float* __restrict__ ut, const float* __restrict__ it,
    const float* __restrict__ W1, int head, float* __restrict__ h1h) {
  __shared__ __align__(16) float xs[64][68];   // xs[k][row]
  __shared__ __align__(16) float wsh[64][68];  // wsh[k][col]
  const int t = threadIdx.x;
  const int rb = blockIdx.x;
  const int j = t & 15;   // col group (4 cols)
  const int i = t >> 4;   // row group (4 rows)

#pragma unroll
  for (int u = 0; u < 4; ++u) {
    int idx = t + u * 256;          // 0..1023
    int row = idx >> 4;             // 0..63
    int f4 = idx & 15;
    int grow = rb * 64 + row;
    float4 v = make_float4(0.f, 0.f, 0.f, 0.f);
    if (grow < NUM_NODES) {
      const float* xr = (grow < NUM_USERS) ? ut + (size_t)grow * 64
                                           : it + (size_t)(grow - NUM_USERS) * 64;
      v = *(const float4*)(xr + f4 * 4);
    }
    xs[f4 * 4 + 0][row] = v.x;
    xs[f4 * 4 + 1][row] = v.y;
    xs[f4 * 4 + 2][row] = v.z;
    xs[f4 * 4 + 3][row] = v.w;
    float4 wv = *(const float4*)(W1 + (size_t)row * 256 + head * 64 + f4 * 4);
    *(float4*)&wsh[row][f4 * 4] = wv;
  }
  __syncthreads();

  float acc[4][4] = {{0.f,0.f,0.f,0.f},{0.f,0.f,0.f,0.f},{0.f,0.f,0.f,0.f},{0.f,0.f,0.f,0.f}};
#pragma unroll
  for (int k = 0; k < 64; ++k) {
    float4 av = *(const float4*)&xs[k][i * 4];
    float4 bv = *(const float4*)&wsh[k][j * 4];
    acc[0][0] += av.x * bv.x; acc[0][1] += av.x * bv.y; acc[0][2] += av.x * bv.z; acc[0][3] += av.x * bv.w;
    acc[1][0] += av.y * bv.x; acc[1][1] += av.y * bv.y; acc[1][2] += av.y * bv.z; acc[1][3] += av.y * bv.w;
    acc[2][0] += av.z * bv.x; acc[2][1] += av.z * bv.y; acc[2][2] += av.z * bv.z; acc[2][3] += av.z * bv.w;
    acc[3][0] += av.w * bv.x; acc[3][1] += av.w * bv.y; acc[3][2] += av.w * bv.z; acc[3][3] += av.w * bv.w;
  }

#pragma unroll
  for (int r = 0; r < 4; ++r) {
    int grow = rb * 64 + i * 4 + r;
    if (grow < NUM_NODES) {
      float4 o = make_float4(acc[r][0], acc[r][1], acc[r][2], acc[r][3]);
      *(float4*)(h1h + (size_t)grow * 64 + j * 4) = o;
    }
  }
}

// ---------------- fused: per-head softmax-agg + ELU + partial GEMM2 into h2 ----------------
__global__ __launch_bounds__(256) void agg1g2_kernel(
    const int* __restrict__ offsets, const int* __restrict__ srcs,
    const float* __restrict__ e1s, const float* __restrict__ e1d,
    const unsigned* __restrict__ gkey,
    const float* __restrict__ h1h, const float* __restrict__ W2,
    int head, int first, float* __restrict__ h2) {
  __shared__ float w2s[64][64];  // W2[h*64+k][j]; 2-way LDS aliasing is free
  const int t = threadIdx.x;
#pragma unroll
  for (int u = 0; u < 16; ++u) {
    int idx = t + u * 256;       // 0..4095
    int k = idx >> 6, jj = idx & 63;
    w2s[k][jj] = W2[(size_t)(head * 64 + k) * 64 + jj];
  }
  __syncthreads();

  int wid = t >> 6, lane = t & 63;
  int node = blockIdx.x * 4 + wid;
  if (node >= NUM_NODES) return;
  float gmax = key2f(*gkey);
  int beg = offsets[node], end = offsets[node + 1];
  float edv = e1d[(size_t)node * 4 + head];

  // pass 1: lane-parallel sum of exp
  float psum = 0.f;
  for (int e = beg + lane; e < end; e += 64) {
    int s = srcs[e];
    float x = e1s[(size_t)s * 4 + head] + edv;
    x = x > 0.f ? x : 0.2f * x;
    psum += __expf(x - gmax);
  }
#pragma unroll
  for (int off = 32; off; off >>= 1) psum += __shfl_xor(psum, off, 64);
  float inv = 1.f / (psum + 1e-8f);

  // pass 2: feature-parallel weighted gather
  float acc = 0.f;
  for (int e = beg; e < end; ++e) {
    int s = srcs[e];
    float x = e1s[(size_t)s * 4 + head] + edv;
    x = x > 0.f ? x : 0.2f * x;
    float w = __expf(x - gmax) * inv;
    acc += w * h1h[(size_t)s * 64 + lane];
  }
  // ELU
  acc = acc > 0.f ? acc : expm1f(acc);

  // partial GEMM2: h2[node, j] += sum_k elu_k * W2[h*64+k, j]
  float sum2 = 0.f;
#pragma unroll
  for (int k = 0; k < 64; ++k) {
    float ek = __shfl(acc, k, 64);
    sum2 += ek * w2s[k][lane];
  }
  float prev = first ? 0.f : h2[(size_t)node * 64 + lane];
  h2[(size_t)node * 64 + lane] = prev + sum2;
}

// ---------------- e2 tables from h2: e2s[n] = h2_n . a2[:64], e2d with a2[64:] ----------------
__global__ __launch_bounds__(256) void e2_kernel(
    const float* __restrict__ h2, const float* __restrict__ a2,
    float* __restrict__ e2s, float* __restrict__ e2d) {
  int wid = threadIdx.x >> 6, lane = threadIdx.x & 63;
  int node = blockIdx.x * 4 + wid;
  if (node >= NUM_NODES) return;
  float hv = h2[(size_t)node * 64 + lane];
  float ps = hv * a2[lane];
  float pd = hv * a2[64 + lane];
#pragma unroll
  for (int off = 32; off; off >>= 1) {
    ps += __shfl_xor(ps, off, 64);
    pd += __shfl_xor(pd, off, 64);
  }
  if (lane == 0) { e2s[node] = ps; e2d[node] = pd; }
}

// ---------------- layer-2 aggregation + residual ----------------
__global__ __launch_bounds__(256) void agg2_kernel(
    const int* __restrict__ offsets, const int* __restrict__ srcs,
    const float* __restrict__ e2s, const float* __restrict__ e2d,
    const unsigned* __restrict__ gkey,
    const float* __restrict__ h2,
    const float* __restrict__ ut, const float* __restrict__ it,
    float* __restrict__ hfin) {
  int wid = threadIdx.x >> 6, lane = threadIdx.x & 63;
  int node = blockIdx.x * 4 + wid;
  if (node >= NUM_NODES) return;
  float gmax = key2f(*gkey);
  int beg = offsets[node], end = offsets[node + 1];
  float edv = e2d[node];

  float psum = 0.f;
  for (int e = beg + lane; e < end; e += 64) {
    int s = srcs[e];
    float x = e2s[s] + edv;
    x = x > 0.f ? x : 0.2f * x;
    psum += __expf(x - gmax);
  }
#pragma unroll
  for (int off = 32; off; off >>= 1) psum += __shfl_xor(psum, off, 64);
  float inv = 1.f / (psum + 1e-8f);

  float acc = 0.f;
  for (int e = beg; e < end; ++e) {
    int s = srcs[e];
    float x = e2s[s] + edv;
    x = x > 0.f ? x : 0.2f * x;
    acc += __expf(x - gmax) * inv * h2[(size_t)s * 64 + lane];
  }
  float res = (node < NUM_USERS) ? ut[(size_t)node * 64 + lane]
                                 : it[(size_t)(node - NUM_USERS) * 64 + lane];
  hfin[(size_t)node * 64 + lane] = acc + res;
}

// ---------------- final batched dot ----------------
__global__ __launch_bounds__(256) void final_kernel(
    const float* __restrict__ hf, const int* __restrict__ uid,
    const int* __restrict__ iid, float* __restrict__ out) {
  int wid = threadIdx.x >> 6, lane = threadIdx.x & 63;
  int idx = blockIdx.x * 4 + wid;
  if (idx >= BATCH) return;
  int u = uid[idx], v = iid[idx];
  float a = hf[(size_t)u * 64 + lane];
  float b = hf[(size_t)(NUM_USERS + v) * 64 + lane];
  float p = a * b;
#pragma unroll
  for (int off = 32; off; off >>= 1) p += __shfl_xor(p, off, 64);
  if (lane == 0) out[idx] = p;
}

extern "C" void kernel_launch(void* const* d_in, const int* in_sizes, int n_in,
                              void* d_out, int out_size, void* d_ws, size_t ws_size,
                              hipStream_t stream) {
  const float* user_table = (const float*)d_in[0];
  const float* item_table = (const float*)d_in[1];
  const float* W1 = (const float*)d_in[2];
  const float* a1 = (const float*)d_in[3];
  const float* W2 = (const float*)d_in[4];
  const float* a2 = (const float*)d_in[5];
  const int* edge_index = (const int*)d_in[6];
  const int* user_ids = (const int*)d_in[7];
  const int* item_ids = (const int*)d_in[8];
  float* out = (float*)d_out;

  const int* src = edge_index;
  const int* dst = edge_index + NUM_EDGES;

  // ---- workspace layout (~93 MB peak) ----
  float* ws = (float*)d_ws;
  float* h1h = ws;                                  // 150000*64 (reused per head; hfin aliases)
  float* h2 = h1h + (size_t)NUM_NODES * 64;         // 150000*64
  float* e1s = h2 + (size_t)NUM_NODES * 64;         // 150000*4
  float* e1d = e1s + (size_t)NUM_NODES * 4;         // 150000*4
  float* e2s = e1d + (size_t)NUM_NODES * 4;         // 150000
  float* e2d = e2s + NUM_NODES;                     // 150000
  float* w1a = e2d + NUM_NODES;                     // 256
  float* w1b = w1a + 256;                           // 256
  int* count = (int*)(w1b + 256);                   // 150000
  int* offsets = count + NUM_NODES;                 // 150001
  int* cursor = offsets + NUM_NODES + 1;            // 150000
  int* srcs = cursor + NUM_NODES;                   // 2000000
  unsigned* gkeys = (unsigned*)(srcs + NUM_EDGES);  // 2
  float* hfin = h1h;                                // alias: h1h dead after last agg1g2

  const int eb = (NUM_EDGES + 255) / 256;
  const int nb4 = (NUM_NODES + 3) / 4;      // wave-per-node grids
  const int nb64 = (NUM_NODES + 63) / 64;   // gemm tile grid

  zero_kernel<<<(NUM_NODES + 255) / 256, 256, 0, stream>>>(count, gkeys);
  hist_kernel<<<eb, 256, 0, stream>>>(dst, count);
  scan_kernel<<<1, 1024, 0, stream>>>(count, offsets, cursor);
  scatter_kernel<<<eb, 256, 0, stream>>>(src, dst, cursor, srcs);

  proj1_kernel<<<1, 256, 0, stream>>>(W1, a1, w1a, w1b);
  e1_kernel<<<nb4, 256, 0, stream>>>(user_table, item_table, w1a, w1b, e1s, e1d);
  maxatt_kernel<4><<<1024, 256, 0, stream>>>(src, dst, e1s, e1d, gkeys + 0);

  for (int h = 0; h < 4; ++h) {
    gemm1_kernel<<<nb64, 256, 0, stream>>>(user_table, item_table, W1, h, h1h);
    agg1g2_kernel<<<nb4, 256, 0, stream>>>(offsets, srcs, e1s, e1d, gkeys + 0,
                                           h1h, W2, h, (h == 0) ? 1 : 0, h2);
  }

  e2_kernel<<<nb4, 256, 0, stream>>>(h2, a2, e2s, e2d);
  maxatt_kernel<1><<<1024, 256, 0, stream>>>(src, dst, e2s, e2d, gkeys + 1);
  agg2_kernel<<<nb4, 256, 0, stream>>>(offsets, srcs, e2s, e2d, gkeys + 1, h2,
                                       user_table, item_table, hfin);
  final_kernel<<<(BATCH + 3) / 4, 256, 0, stream>>>(hfin, user_ids, item_ids, out);
}

// Round 3
// 1992.493 us; speedup vs baseline: 1.7621x; 1.7621x over previous
//
#include <hip/hip_runtime.h>
#include <hip/hip_bf16.h>
#include <cstdint>
#include <cstddef>

#define NUM_USERS 100000
#define NUM_ITEMS 50000
#define NUM_NODES 150000
#define NUM_EDGES 2000000
#define BATCH 16384

// ---- monotone float<->uint key for atomicMax on floats (zero-init == -inf) ----
__device__ __forceinline__ unsigned f2key(float f) {
  unsigned u = __float_as_uint(f);
  return (u & 0x80000000u) ? ~u : (u | 0x80000000u);
}
__device__ __forceinline__ float key2f(unsigned k) {
  unsigned u = (k & 0x80000000u) ? (k & 0x7fffffffu) : ~k;
  return __uint_as_float(u);
}

// ---------------- init (no hipMemsetAsync anywhere) ----------------
__global__ void zero_kernel(int* __restrict__ count, int* __restrict__ flags,
                            unsigned* __restrict__ gkeys) {
  int i = blockIdx.x * blockDim.x + threadIdx.x;
  if (i < NUM_NODES) { count[i] = 0; flags[i] = 0; }
  if (i < 2) gkeys[i] = 0u;
}

__global__ void flag_kernel(const int* __restrict__ uid, const int* __restrict__ iid,
                            int* __restrict__ flags) {
  int i = blockIdx.x * blockDim.x + threadIdx.x;
  if (i < BATCH) {
    flags[uid[i]] = 1;
    flags[NUM_USERS + iid[i]] = 1;
  }
}

// ---------------- CSR construction ----------------
__global__ void hist_kernel(const int* __restrict__ dst, int* __restrict__ count) {
  int e = blockIdx.x * blockDim.x + threadIdx.x;
  if (e < NUM_EDGES) atomicAdd(&count[dst[e]], 1);
}

__global__ void scan_kernel(const int* __restrict__ count, int* __restrict__ offsets,
                            int* __restrict__ cursor) {
  __shared__ int ssum[1024];
  const int n = NUM_NODES;
  int t = threadIdx.x;
  const int chunk = (n + 1023) >> 10;
  int b = t * chunk;
  int e = b + chunk; if (e > n) e = n;
  if (b > n) b = n;
  int s = 0;
  for (int i = b; i < e; ++i) s += count[i];
  ssum[t] = s;
  __syncthreads();
  for (int off = 1; off < 1024; off <<= 1) {
    int v = 0;
    if (t >= off) v = ssum[t - off];
    __syncthreads();
    if (t >= off) ssum[t] += v;
    __syncthreads();
  }
  int run = (t == 0) ? 0 : ssum[t - 1];
  for (int i = b; i < e; ++i) {
    offsets[i] = run;
    cursor[i] = run;
    run += count[i];
  }
  if (t == 1023) offsets[n] = ssum[1023];  // == NUM_EDGES
}

__global__ void scatter_kernel(const int* __restrict__ src, const int* __restrict__ dst,
                               int* __restrict__ cursor, int* __restrict__ src_sorted) {
  int e = blockIdx.x * blockDim.x + threadIdx.x;
  if (e < NUM_EDGES) {
    int p = atomicAdd(&cursor[dst[e]], 1);
    src_sorted[p] = src[e];
  }
}

// ---------------- projected attention vectors: w1a[h][k] = sum_f W1[k, h*64+f]*a_l[h,f]
__global__ void proj1_kernel(const float* __restrict__ W1, const float* __restrict__ a1,
                             float* __restrict__ w1a, float* __restrict__ w1b) {
  int t = threadIdx.x;  // 256 threads: h = t>>6, k = t&63
  int h = t >> 6, k = t & 63;
  float sa = 0.f, sb = 0.f;
  for (int f = 0; f < 64; ++f) {
    float w = W1[(size_t)k * 256 + h * 64 + f];
    sa += w * a1[h * 128 + f];
    sb += w * a1[h * 128 + 64 + f];
  }
  w1a[h * 64 + k] = sa;
  w1b[h * 64 + k] = sb;
}

// ---------------- e1 tables straight from embeddings ----------------
__global__ __launch_bounds__(256) void e1_kernel(
    const float* __restrict__ ut, const float* __restrict__ it,
    const float* __restrict__ w1a, const float* __restrict__ w1b,
    float* __restrict__ e1s, float* __restrict__ e1d) {
  int wid = threadIdx.x >> 6, lane = threadIdx.x & 63;
  int node = blockIdx.x * 4 + wid;
  if (node >= NUM_NODES) return;
  const float* x = (node < NUM_USERS) ? ut + (size_t)node * 64
                                      : it + (size_t)(node - NUM_USERS) * 64;
  float xv = x[lane];
#pragma unroll
  for (int h = 0; h < 4; ++h) {
    float ps = xv * w1a[h * 64 + lane];
    float pd = xv * w1b[h * 64 + lane];
#pragma unroll
    for (int off = 32; off; off >>= 1) {
      ps += __shfl_xor(ps, off, 64);
      pd += __shfl_xor(pd, off, 64);
    }
    if (lane == 0) {
      e1s[(size_t)node * 4 + h] = ps;
      e1d[(size_t)node * 4 + h] = pd;
    }
  }
}

// ---------------- global max of leaky-relu attention logits ----------------
template <int HEADS>
__global__ __launch_bounds__(256) void maxatt_kernel(
    const int* __restrict__ src, const int* __restrict__ dst,
    const float* __restrict__ es, const float* __restrict__ ed,
    unsigned* __restrict__ gkey) {
  float m = -3.4e38f;
  int stride = gridDim.x * blockDim.x;
  for (int e = blockIdx.x * blockDim.x + threadIdx.x; e < NUM_EDGES; e += stride) {
    int s = src[e], d = dst[e];
#pragma unroll
    for (int h = 0; h < HEADS; ++h) {
      float v = es[(size_t)s * HEADS + h] + ed[(size_t)d * HEADS + h];
      v = v > 0.f ? v : 0.2f * v;
      m = fmaxf(m, v);
    }
  }
#pragma unroll
  for (int off = 32; off; off >>= 1) m = fmaxf(m, __shfl_xor(m, off, 64));
  if ((threadIdx.x & 63) == 0) atomicMax(gkey, f2key(m));
}

// ---- vector load of HC consecutive e-table entries for node s ----
template <int HC>
__device__ __forceinline__ void ld_e(const float* __restrict__ e, int s, int hbase,
                                     float out[HC]) {
  if constexpr (HC == 4) {
    float4 v = *(const float4*)(e + (size_t)s * 4);
    out[0] = v.x; out[1] = v.y; out[2] = v.z; out[3] = v.w;
  } else if constexpr (HC == 2) {
    float2 v = *(const float2*)(e + (size_t)s * 4 + hbase);
    out[0] = v.x; out[1] = v.y;
  } else {
    out[0] = e[(size_t)s * 4 + hbase];
  }
}

// ---------------- edge pass: attention-weighted aggregation of RAW embeddings ----------------
// aggX[node][h*64+f] = sum_e softmax_att(h,e) * X[src_e][f]   (heads hbase..hbase+HC-1)
// Exploits linearity: segment_sum(att * (X@W1)[src]) == segment_sum(att * X[src]) @ W1.
template <int HC>
__global__ __launch_bounds__(256) void aggX_kernel(
    const int* __restrict__ offsets, const int* __restrict__ srcs,
    const float* __restrict__ e1s, const float* __restrict__ e1d,
    const unsigned* __restrict__ gkey,
    const float* __restrict__ ut, const float* __restrict__ it,
    int hbase, float* __restrict__ aggX) {
  int wid = threadIdx.x >> 6, lane = threadIdx.x & 63;
  int node = blockIdx.x * 4 + wid;
  if (node >= NUM_NODES) return;
  float gmax = key2f(*gkey);
  int beg = offsets[node], end = offsets[node + 1];
  float edv[HC];
#pragma unroll
  for (int h = 0; h < HC; ++h) edv[h] = e1d[(size_t)node * 4 + hbase + h];

  // pass 1: lane-parallel exp-sums per head
  float sums[HC];
#pragma unroll
  for (int h = 0; h < HC; ++h) sums[h] = 0.f;
  for (int e = beg + lane; e < end; e += 64) {
    int s = srcs[e];
    float ev[HC];
    ld_e<HC>(e1s, s, hbase, ev);
#pragma unroll
    for (int h = 0; h < HC; ++h) {
      float x = ev[h] + edv[h];
      x = x > 0.f ? x : 0.2f * x;
      sums[h] += __expf(x - gmax);
    }
  }
#pragma unroll
  for (int h = 0; h < HC; ++h) {
#pragma unroll
    for (int off = 32; off; off >>= 1) sums[h] += __shfl_xor(sums[h], off, 64);
  }
  float inv[HC];
#pragma unroll
  for (int h = 0; h < HC; ++h) inv[h] = 1.f / (sums[h] + 1e-8f);

  // pass 2: feature-parallel weighted gather of raw embedding rows (unroll x2 for MLP)
  float acc[HC];
#pragma unroll
  for (int h = 0; h < HC; ++h) acc[h] = 0.f;
  int e = beg;
  for (; e + 2 <= end; e += 2) {
    int s0 = srcs[e], s1 = srcs[e + 1];
    float ev0[HC], ev1[HC];
    ld_e<HC>(e1s, s0, hbase, ev0);
    ld_e<HC>(e1s, s1, hbase, ev1);
    const float* xp0 = (s0 < NUM_USERS) ? ut + (size_t)s0 * 64
                                        : it + (size_t)(s0 - NUM_USERS) * 64;
    const float* xp1 = (s1 < NUM_USERS) ? ut + (size_t)s1 * 64
                                        : it + (size_t)(s1 - NUM_USERS) * 64;
    float xv0 = xp0[lane], xv1 = xp1[lane];
#pragma unroll
    for (int h = 0; h < HC; ++h) {
      float x0 = ev0[h] + edv[h]; x0 = x0 > 0.f ? x0 : 0.2f * x0;
      float x1 = ev1[h] + edv[h]; x1 = x1 > 0.f ? x1 : 0.2f * x1;
      acc[h] += __expf(x0 - gmax) * inv[h] * xv0 + __expf(x1 - gmax) * inv[h] * xv1;
    }
  }
  if (e < end) {
    int s0 = srcs[e];
    float ev0[HC];
    ld_e<HC>(e1s, s0, hbase, ev0);
    const float* xp0 = (s0 < NUM_USERS) ? ut + (size_t)s0 * 64
                                        : it + (size_t)(s0 - NUM_USERS) * 64;
    float xv0 = xp0[lane];
#pragma unroll
    for (int h = 0; h < HC; ++h) {
      float x0 = ev0[h] + edv[h]; x0 = x0 > 0.f ? x0 : 0.2f * x0;
      acc[h] += __expf(x0 - gmax) * inv[h] * xv0;
    }
  }
#pragma unroll
  for (int h = 0; h < HC; ++h)
    aggX[(size_t)node * (HC * 64) + h * 64 + lane] = acc[h];
}

// ---------------- dense transform: h2 += elu(aggX_h @ W1_h) @ W2_h, fused e2 on last ----------------
template <int HC>
__global__ __launch_bounds__(256) void trans_kernel(
    const float* __restrict__ aggX, const float* __restrict__ W1,
    const float* __restrict__ W2, const float* __restrict__ a2,
    int hbase, int last,
    float* __restrict__ h2, float* __restrict__ e2s, float* __restrict__ e2d) {
  __shared__ __align__(16) float xs[64][68];
  __shared__ __align__(16) float wsm[64][68];
  const int t = threadIdx.x;
  const int rb = blockIdx.x;
  const int j = t & 15, i = t >> 4;

  float acc2[4][4];
  if (hbase == 0) {
#pragma unroll
    for (int r = 0; r < 4; ++r) { acc2[r][0] = 0.f; acc2[r][1] = 0.f; acc2[r][2] = 0.f; acc2[r][3] = 0.f; }
  } else {
#pragma unroll
    for (int r = 0; r < 4; ++r) {
      int grow = rb * 64 + i * 4 + r;
      float4 v = make_float4(0.f, 0.f, 0.f, 0.f);
      if (grow < NUM_NODES) v = *(const float4*)(h2 + (size_t)grow * 64 + j * 4);
      acc2[r][0] = v.x; acc2[r][1] = v.y; acc2[r][2] = v.z; acc2[r][3] = v.w;
    }
  }

  for (int h = 0; h < HC; ++h) {
    if (h) __syncthreads();
    // stage aggX block (head-h slice, transposed) + W1 head slice
#pragma unroll
    for (int u = 0; u < 4; ++u) {
      int idx = t + u * 256;
      int row = idx >> 4, f4 = idx & 15;
      int grow = rb * 64 + row;
      float4 v = make_float4(0.f, 0.f, 0.f, 0.f);
      if (grow < NUM_NODES)
        v = *(const float4*)(aggX + (size_t)grow * (HC * 64) + h * 64 + f4 * 4);
      xs[f4 * 4 + 0][row] = v.x;
      xs[f4 * 4 + 1][row] = v.y;
      xs[f4 * 4 + 2][row] = v.z;
      xs[f4 * 4 + 3][row] = v.w;
      float4 wv = *(const float4*)(W1 + (size_t)row * 256 + (hbase + h) * 64 + f4 * 4);
      *(float4*)&wsm[row][f4 * 4] = wv;
    }
    __syncthreads();

    float t1[4][4] = {{0.f,0.f,0.f,0.f},{0.f,0.f,0.f,0.f},{0.f,0.f,0.f,0.f},{0.f,0.f,0.f,0.f}};
#pragma unroll
    for (int k = 0; k < 64; ++k) {
      float4 av = *(const float4*)&xs[k][i * 4];
      float4 bv = *(const float4*)&wsm[k][j * 4];
      t1[0][0] += av.x * bv.x; t1[0][1] += av.x * bv.y; t1[0][2] += av.x * bv.z; t1[0][3] += av.x * bv.w;
      t1[1][0] += av.y * bv.x; t1[1][1] += av.y * bv.y; t1[1][2] += av.y * bv.z; t1[1][3] += av.y * bv.w;
      t1[2][0] += av.z * bv.x; t1[2][1] += av.z * bv.y; t1[2][2] += av.z * bv.z; t1[2][3] += av.z * bv.w;
      t1[3][0] += av.w * bv.x; t1[3][1] += av.w * bv.y; t1[3][2] += av.w * bv.z; t1[3][3] += av.w * bv.w;
    }
    __syncthreads();

    // write elu(T) transposed into xs (becomes A of second multiply); stage W2 head slice
#pragma unroll
    for (int r = 0; r < 4; ++r)
#pragma unroll
      for (int c = 0; c < 4; ++c) {
        float v = t1[r][c];
        xs[j * 4 + c][i * 4 + r] = v > 0.f ? v : expm1f(v);
      }
#pragma unroll
    for (int u = 0; u < 4; ++u) {
      int idx = t + u * 256;
      int row = idx >> 4, f4 = idx & 15;
      float4 wv = *(const float4*)(W2 + (size_t)((hbase + h) * 64 + row) * 64 + f4 * 4);
      *(float4*)&wsm[row][f4 * 4] = wv;
    }
    __syncthreads();

#pragma unroll
    for (int k = 0; k < 64; ++k) {
      float4 av = *(const float4*)&xs[k][i * 4];
      float4 bv = *(const float4*)&wsm[k][j * 4];
      acc2[0][0] += av.x * bv.x; acc2[0][1] += av.x * bv.y; acc2[0][2] += av.x * bv.z; acc2[0][3] += av.x * bv.w;
      acc2[1][0] += av.y * bv.x; acc2[1][1] += av.y * bv.y; acc2[1][2] += av.y * bv.z; acc2[1][3] += av.y * bv.w;
      acc2[2][0] += av.z * bv.x; acc2[2][1] += av.z * bv.y; acc2[2][2] += av.z * bv.z; acc2[2][3] += av.z * bv.w;
      acc2[3][0] += av.w * bv.x; acc2[3][1] += av.w * bv.y; acc2[3][2] += av.w * bv.z; acc2[3][3] += av.w * bv.w;
    }
  }

  // store h2 tile
#pragma unroll
  for (int r = 0; r < 4; ++r) {
    int grow = rb * 64 + i * 4 + r;
    if (grow < NUM_NODES) {
      float4 o = make_float4(acc2[r][0], acc2[r][1], acc2[r][2], acc2[r][3]);
      *(float4*)(h2 + (size_t)grow * 64 + j * 4) = o;
    }
  }

  // fused e2 projections once h2 is complete
  if (last) {
    const float4 alv = *(const float4*)(a2 + j * 4);
    const float4 arv = *(const float4*)(a2 + 64 + j * 4);
#pragma unroll
    for (int r = 0; r < 4; ++r) {
      float ps = acc2[r][0] * alv.x + acc2[r][1] * alv.y + acc2[r][2] * alv.z + acc2[r][3] * alv.w;
      float pd = acc2[r][0] * arv.x + acc2[r][1] * arv.y + acc2[r][2] * arv.z + acc2[r][3] * arv.w;
#pragma unroll
      for (int off = 1; off < 16; off <<= 1) {
        ps += __shfl_xor(ps, off, 64);
        pd += __shfl_xor(pd, off, 64);
      }
      if (j == 0) {
        int grow = rb * 64 + i * 4 + r;
        if (grow < NUM_NODES) { e2s[grow] = ps; e2d[grow] = pd; }
      }
    }
  }
}

// ---------------- layer-2 aggregation + residual (flagged nodes only) ----------------
__global__ __launch_bounds__(256) void agg2_kernel(
    const int* __restrict__ offsets, const int* __restrict__ srcs,
    const float* __restrict__ e2s, const float* __restrict__ e2d,
    const unsigned* __restrict__ gkey, const int* __restrict__ flags,
    const float* __restrict__ h2,
    const float* __restrict__ ut, const float* __restrict__ it,
    float* __restrict__ hfin) {
  int wid = threadIdx.x >> 6, lane = threadIdx.x & 63;
  int node = blockIdx.x * 4 + wid;
  if (node >= NUM_NODES) return;
  if (!flags[node]) return;  // output never read for this node
  float gmax = key2f(*gkey);
  int beg = offsets[node], end = offsets[node + 1];
  float edv = e2d[node];

  float psum = 0.f;
  for (int e = beg + lane; e < end; e += 64) {
    int s = srcs[e];
    float x = e2s[s] + edv;
    x = x > 0.f ? x : 0.2f * x;
    psum += __expf(x - gmax);
  }
#pragma unroll
  for (int off = 32; off; off >>= 1) psum += __shfl_xor(psum, off, 64);
  float inv = 1.f / (psum + 1e-8f);

  float acc = 0.f;
  int e = beg;
  for (; e + 2 <= end; e += 2) {
    int s0 = srcs[e], s1 = srcs[e + 1];
    float x0 = e2s[s0] + edv; x0 = x0 > 0.f ? x0 : 0.2f * x0;
    float x1 = e2s[s1] + edv; x1 = x1 > 0.f ? x1 : 0.2f * x1;
    float hv0 = h2[(size_t)s0 * 64 + lane];
    float hv1 = h2[(size_t)s1 * 64 + lane];
    acc += __expf(x0 - gmax) * inv * hv0 + __expf(x1 - gmax) * inv * hv1;
  }
  if (e < end) {
    int s0 = srcs[e];
    float x0 = e2s[s0] + edv; x0 = x0 > 0.f ? x0 : 0.2f * x0;
    acc += __expf(x0 - gmax) * inv * h2[(size_t)s0 * 64 + lane];
  }
  float res = (node < NUM_USERS) ? ut[(size_t)node * 64 + lane]
                                 : it[(size_t)(node - NUM_USERS) * 64 + lane];
  hfin[(size_t)node * 64 + lane] = acc + res;
}

// ---------------- final batched dot ----------------
__global__ __launch_bounds__(256) void final_kernel(
    const float* __restrict__ hf, const int* __restrict__ uid,
    const int* __restrict__ iid, float* __restrict__ out) {
  int wid = threadIdx.x >> 6, lane = threadIdx.x & 63;
  int idx = blockIdx.x * 4 + wid;
  if (idx >= BATCH) return;
  int u = uid[idx], v = iid[idx];
  float a = hf[(size_t)u * 64 + lane];
  float b = hf[(size_t)(NUM_USERS + v) * 64 + lane];
  float p = a * b;
#pragma unroll
  for (int off = 32; off; off >>= 1) p += __shfl_xor(p, off, 64);
  if (lane == 0) out[idx] = p;
}

extern "C" void kernel_launch(void* const* d_in, const int* in_sizes, int n_in,
                              void* d_out, int out_size, void* d_ws, size_t ws_size,
                              hipStream_t stream) {
  const float* user_table = (const float*)d_in[0];
  const float* item_table = (const float*)d_in[1];
  const float* W1 = (const float*)d_in[2];
  const float* a1 = (const float*)d_in[3];
  const float* W2 = (const float*)d_in[4];
  const float* a2 = (const float*)d_in[5];
  const int* edge_index = (const int*)d_in[6];
  const int* user_ids = (const int*)d_in[7];
  const int* item_ids = (const int*)d_in[8];
  float* out = (float*)d_out;

  const int* src = edge_index;
  const int* dst = edge_index + NUM_EDGES;

  // ---- workspace layout (elements), aggX sized by ws_size ----
  float* ws = (float*)d_ws;
  size_t off = 0;
  auto falloc = [&](size_t n) { float* p = ws + off; off += n; return p; };
  float* h2  = falloc((size_t)NUM_NODES * 64);
  float* e1s = falloc((size_t)NUM_NODES * 4);
  float* e1d = falloc((size_t)NUM_NODES * 4);
  float* e2s = falloc(NUM_NODES);
  float* e2d = falloc(NUM_NODES);
  float* w1a = falloc(256);
  float* w1b = falloc(256);
  int* count   = (int*)falloc(NUM_NODES);
  int* offsets = (int*)falloc(NUM_NODES + 1);
  int* cursor  = (int*)falloc(NUM_NODES);
  int* srcs    = (int*)falloc(NUM_EDGES);
  int* flags   = (int*)falloc(NUM_NODES);
  unsigned* gkeys = (unsigned*)falloc(2);
  off = (off + 3) & ~(size_t)3;  // 16B-align aggX for float4 access
  float* aggX = ws + off;
  size_t availElems = (ws_size / 4 > off) ? (ws_size / 4 - off) : 0;

  // head-chunk size: 4 heads in one edge pass if aggX fits, else 2, else 1
  int HC = 1;
  if (availElems >= (size_t)NUM_NODES * 256) HC = 4;
  else if (availElems >= (size_t)NUM_NODES * 128) HC = 2;
  float* hfin = aggX;  // alias: aggX dead after last trans pass

  const int eb = (NUM_EDGES + 255) / 256;
  const int nb4 = (NUM_NODES + 3) / 4;
  const int nb64 = (NUM_NODES + 63) / 64;

  zero_kernel<<<(NUM_NODES + 255) / 256, 256, 0, stream>>>(count, flags, gkeys);
  flag_kernel<<<(BATCH + 255) / 256, 256, 0, stream>>>(user_ids, item_ids, flags);
  hist_kernel<<<eb, 256, 0, stream>>>(dst, count);
  scan_kernel<<<1, 1024, 0, stream>>>(count, offsets, cursor);
  scatter_kernel<<<eb, 256, 0, stream>>>(src, dst, cursor, srcs);

  proj1_kernel<<<1, 256, 0, stream>>>(W1, a1, w1a, w1b);
  e1_kernel<<<nb4, 256, 0, stream>>>(user_table, item_table, w1a, w1b, e1s, e1d);
  maxatt_kernel<4><<<1024, 256, 0, stream>>>(src, dst, e1s, e1d, gkeys + 0);

  for (int hbase = 0; hbase < 4; hbase += HC) {
    int last = (hbase + HC == 4) ? 1 : 0;
    switch (HC) {
      case 4:
        aggX_kernel<4><<<nb4, 256, 0, stream>>>(offsets, srcs, e1s, e1d, gkeys + 0,
                                                user_table, item_table, hbase, aggX);
        trans_kernel<4><<<nb64, 256, 0, stream>>>(aggX, W1, W2, a2, hbase, last,
                                                  h2, e2s, e2d);
        break;
      case 2:
        aggX_kernel<2><<<nb4, 256, 0, stream>>>(offsets, srcs, e1s, e1d, gkeys + 0,
                                                user_table, item_table, hbase, aggX);
        trans_kernel<2><<<nb64, 256, 0, stream>>>(aggX, W1, W2, a2, hbase, last,
                                                  h2, e2s, e2d);
        break;
      default:
        aggX_kernel<1><<<nb4, 256, 0, stream>>>(offsets, srcs, e1s, e1d, gkeys + 0,
                                                user_table, item_table, hbase, aggX);
        trans_kernel<1><<<nb64, 256, 0, stream>>>(aggX, W1, W2, a2, hbase, last,
                                                  h2, e2s, e2d);
        break;
    }
  }

  maxatt_kernel<1><<<1024, 256, 0, stream>>>(src, dst, e2s, e2d, gkeys + 1);
  agg2_kernel<<<nb4, 256, 0, stream>>>(offsets, srcs, e2s, e2d, gkeys + 1, flags,
                                       h2, user_table, item_table, hfin);
  final_kernel<<<(BATCH + 3) / 4, 256, 0, stream>>>(hfin, user_ids, item_ids, out);
}

// Round 4
// 1734.609 us; speedup vs baseline: 2.0241x; 1.1487x over previous
//
#include <hip/hip_runtime.h>
#include <cstdint>
#include <cstddef>

#define NUM_USERS 100000
#define NUM_ITEMS 50000
#define NUM_NODES 150000
#define NUM_EDGES 2000000
#define BATCH 16384

// ---------------- init (no hipMemsetAsync anywhere) ----------------
__global__ void zero_kernel(int* __restrict__ count, int* __restrict__ flags) {
  int i = blockIdx.x * blockDim.x + threadIdx.x;
  if (i < NUM_NODES) { count[i] = 0; flags[i] = 0; }
}

__global__ void flag_kernel(const int* __restrict__ uid, const int* __restrict__ iid,
                            int* __restrict__ flags) {
  int i = blockIdx.x * blockDim.x + threadIdx.x;
  if (i < BATCH) {
    flags[uid[i]] = 1;
    flags[NUM_USERS + iid[i]] = 1;
  }
}

// ---------------- CSR construction ----------------
__global__ void hist_kernel(const int* __restrict__ dst, int* __restrict__ count) {
  int e = blockIdx.x * blockDim.x + threadIdx.x;
  if (e < NUM_EDGES) atomicAdd(&count[dst[e]], 1);
}

__global__ void scan_kernel(const int* __restrict__ count, int* __restrict__ offsets,
                            int* __restrict__ cursor) {
  __shared__ int ssum[1024];
  const int n = NUM_NODES;
  int t = threadIdx.x;
  const int chunk = (n + 1023) >> 10;
  int b = t * chunk;
  int e = b + chunk; if (e > n) e = n;
  if (b > n) b = n;
  int s = 0;
  for (int i = b; i < e; ++i) s += count[i];
  ssum[t] = s;
  __syncthreads();
  for (int off = 1; off < 1024; off <<= 1) {
    int v = 0;
    if (t >= off) v = ssum[t - off];
    __syncthreads();
    if (t >= off) ssum[t] += v;
    __syncthreads();
  }
  int run = (t == 0) ? 0 : ssum[t - 1];
  for (int i = b; i < e; ++i) {
    offsets[i] = run;
    cursor[i] = run;
    run += count[i];
  }
  if (t == 1023) offsets[n] = ssum[1023];  // == NUM_EDGES
}

__global__ void scatter_kernel(const int* __restrict__ src, const int* __restrict__ dst,
                               int* __restrict__ cursor, int* __restrict__ src_sorted) {
  int e = blockIdx.x * blockDim.x + threadIdx.x;
  if (e < NUM_EDGES) {
    int p = atomicAdd(&cursor[dst[e]], 1);
    src_sorted[p] = src[e];
  }
}

// ---------------- projected attention vectors: w1a[h][k] = sum_f W1[k, h*64+f]*a_l[h,f]
__global__ void proj1_kernel(const float* __restrict__ W1, const float* __restrict__ a1,
                             float* __restrict__ w1a, float* __restrict__ w1b) {
  int t = threadIdx.x;  // 256 threads: h = t>>6, k = t&63
  int h = t >> 6, k = t & 63;
  float sa = 0.f, sb = 0.f;
  for (int f = 0; f < 64; ++f) {
    float w = W1[(size_t)k * 256 + h * 64 + f];
    sa += w * a1[h * 128 + f];
    sb += w * a1[h * 128 + 64 + f];
  }
  w1a[h * 64 + k] = sa;
  w1b[h * 64 + k] = sb;
}

// ---------------- e1 tables straight from embeddings ----------------
__global__ __launch_bounds__(256) void e1_kernel(
    const float* __restrict__ ut, const float* __restrict__ it,
    const float* __restrict__ w1a, const float* __restrict__ w1b,
    float* __restrict__ e1s, float* __restrict__ e1d) {
  int wid = threadIdx.x >> 6, lane = threadIdx.x & 63;
  int node = blockIdx.x * 4 + wid;
  if (node >= NUM_NODES) return;
  const float* x = (node < NUM_USERS) ? ut + (size_t)node * 64
                                      : it + (size_t)(node - NUM_USERS) * 64;
  float xv = x[lane];
#pragma unroll
  for (int h = 0; h < 4; ++h) {
    float ps = xv * w1a[h * 64 + lane];
    float pd = xv * w1b[h * 64 + lane];
#pragma unroll
    for (int off = 32; off; off >>= 1) {
      ps += __shfl_xor(ps, off, 64);
      pd += __shfl_xor(pd, off, 64);
    }
    if (lane == 0) {
      e1s[(size_t)node * 4 + h] = ps;
      e1d[(size_t)node * 4 + h] = pd;
    }
  }
}

// ---- vector load of HC consecutive e-table entries for node s ----
template <int HC>
__device__ __forceinline__ void ld_e(const float* __restrict__ e, int s, int hbase,
                                     float out[HC]) {
  if constexpr (HC == 4) {
    float4 v = *(const float4*)(e + (size_t)s * 4);
    out[0] = v.x; out[1] = v.y; out[2] = v.z; out[3] = v.w;
  } else if constexpr (HC == 2) {
    float2 v = *(const float2*)(e + (size_t)s * 4 + hbase);
    out[0] = v.x; out[1] = v.y;
  } else {
    out[0] = e[(size_t)s * 4 + hbase];
  }
}

// ---------------- edge pass: attention-weighted aggregation of RAW embeddings ----------------
// aggX[node][h*64+f] = sum_e softmax_att(h,e) * X[src_e][f]   (heads hbase..hbase+HC-1)
// Softmax computed WITHOUT max-shift: logits are O(0.3) (xavier dots), exp is safe,
// and softmax is shift-invariant (epsilon perturbation ~2e-10 relative).
template <int HC>
__global__ __launch_bounds__(256) void aggX_kernel(
    const int* __restrict__ offsets, const int* __restrict__ srcs,
    const float* __restrict__ e1s, const float* __restrict__ e1d,
    const float* __restrict__ ut, const float* __restrict__ it,
    int hbase, float* __restrict__ aggX) {
  int wid = threadIdx.x >> 6, lane = threadIdx.x & 63;
  int node = blockIdx.x * 4 + wid;
  if (node >= NUM_NODES) return;
  int beg = offsets[node], end = offsets[node + 1];
  int deg = end - beg;
  float edv[HC];
#pragma unroll
  for (int h = 0; h < HC; ++h) edv[h] = e1d[(size_t)node * 4 + hbase + h];

  float acc[HC];
#pragma unroll
  for (int h = 0; h < HC; ++h) acc[h] = 0.f;

  if (deg <= 64) {
    // ---- fast path: cache src ids + normalized weights in registers ----
    int s = 0;
    float w[HC];
#pragma unroll
    for (int h = 0; h < HC; ++h) w[h] = 0.f;
    if (lane < deg) {
      s = srcs[beg + lane];
      float ev[HC];
      ld_e<HC>(e1s, s, hbase, ev);
#pragma unroll
      for (int h = 0; h < HC; ++h) {
        float x = ev[h] + edv[h];
        x = x > 0.f ? x : 0.2f * x;
        w[h] = __expf(x);
      }
    }
#pragma unroll
    for (int h = 0; h < HC; ++h) {
      float sum = w[h];
#pragma unroll
      for (int off = 32; off; off >>= 1) sum += __shfl_xor(sum, off, 64);
      w[h] *= 1.f / (sum + 1e-8f);
    }
    // edge walk: no loads in the dependent chain except the row gather itself
    int e = 0;
    for (; e + 2 <= deg; e += 2) {
      int s0 = __shfl(s, e, 64), s1 = __shfl(s, e + 1, 64);
      const float* xp0 = (s0 < NUM_USERS) ? ut + (size_t)s0 * 64
                                          : it + (size_t)(s0 - NUM_USERS) * 64;
      const float* xp1 = (s1 < NUM_USERS) ? ut + (size_t)s1 * 64
                                          : it + (size_t)(s1 - NUM_USERS) * 64;
      float xv0 = xp0[lane], xv1 = xp1[lane];
#pragma unroll
      for (int h = 0; h < HC; ++h)
        acc[h] += __shfl(w[h], e, 64) * xv0 + __shfl(w[h], e + 1, 64) * xv1;
    }
    if (e < deg) {
      int s0 = __shfl(s, e, 64);
      const float* xp0 = (s0 < NUM_USERS) ? ut + (size_t)s0 * 64
                                          : it + (size_t)(s0 - NUM_USERS) * 64;
      float xv0 = xp0[lane];
#pragma unroll
      for (int h = 0; h < HC; ++h) acc[h] += __shfl(w[h], e, 64) * xv0;
    }
  } else {
    // ---- generic fallback (deg > 64): two streaming passes ----
    float sums[HC];
#pragma unroll
    for (int h = 0; h < HC; ++h) sums[h] = 0.f;
    for (int e = beg + lane; e < end; e += 64) {
      int s = srcs[e];
      float ev[HC];
      ld_e<HC>(e1s, s, hbase, ev);
#pragma unroll
      for (int h = 0; h < HC; ++h) {
        float x = ev[h] + edv[h];
        x = x > 0.f ? x : 0.2f * x;
        sums[h] += __expf(x);
      }
    }
#pragma unroll
    for (int h = 0; h < HC; ++h) {
#pragma unroll
      for (int off = 32; off; off >>= 1) sums[h] += __shfl_xor(sums[h], off, 64);
    }
    float inv[HC];
#pragma unroll
    for (int h = 0; h < HC; ++h) inv[h] = 1.f / (sums[h] + 1e-8f);
    for (int e = beg; e < end; ++e) {
      int s0 = srcs[e];
      float ev0[HC];
      ld_e<HC>(e1s, s0, hbase, ev0);
      const float* xp0 = (s0 < NUM_USERS) ? ut + (size_t)s0 * 64
                                          : it + (size_t)(s0 - NUM_USERS) * 64;
      float xv0 = xp0[lane];
#pragma unroll
      for (int h = 0; h < HC; ++h) {
        float x0 = ev0[h] + edv[h];
        x0 = x0 > 0.f ? x0 : 0.2f * x0;
        acc[h] += __expf(x0) * inv[h] * xv0;
      }
    }
  }
#pragma unroll
  for (int h = 0; h < HC; ++h)
    aggX[(size_t)node * (HC * 64) + h * 64 + lane] = acc[h];
}

// ---------------- dense transform: h2 += elu(aggX_h @ W1_h) @ W2_h ----------------
// A-operands in registers; cross-lane A access via __shfl (lane (lane&48)|(k>>2)
// holds A[row][k] in reg [r][k&3]). Only W1/W2 staged in LDS. Fused e2 on last chunk.
template <int HC>
__global__ __launch_bounds__(256) void trans_kernel(
    const float* __restrict__ aggX, const float* __restrict__ W1,
    const float* __restrict__ W2, const float* __restrict__ a2,
    int hbase, int last, float* __restrict__ h2,
    float* __restrict__ e2s, float* __restrict__ e2d) {
  __shared__ __align__(16) float wsm[64][68];
  const int t = threadIdx.x;
  const int rb = blockIdx.x;
  const int lane = t & 63;
  const int j = t & 15, i = t >> 4;
  const int row0 = rb * 64 + i * 4;

  float acc2[4][4];
  if (hbase == 0) {
#pragma unroll
    for (int r = 0; r < 4; ++r) { acc2[r][0] = 0.f; acc2[r][1] = 0.f; acc2[r][2] = 0.f; acc2[r][3] = 0.f; }
  } else {
#pragma unroll
    for (int r = 0; r < 4; ++r) {
      float4 v = make_float4(0.f, 0.f, 0.f, 0.f);
      if (row0 + r < NUM_NODES) v = *(const float4*)(h2 + (size_t)(row0 + r) * 64 + j * 4);
      acc2[r][0] = v.x; acc2[r][1] = v.y; acc2[r][2] = v.z; acc2[r][3] = v.w;
    }
  }

#pragma unroll 1
  for (int h = 0; h < HC; ++h) {
    // A tile into registers: a_[r][c] = aggX[row0+r][h*64 + j*4+c]
    float a_[4][4];
#pragma unroll
    for (int r = 0; r < 4; ++r) {
      float4 v = make_float4(0.f, 0.f, 0.f, 0.f);
      if (row0 + r < NUM_NODES)
        v = *(const float4*)(aggX + (size_t)(row0 + r) * (HC * 64) + h * 64 + j * 4);
      a_[r][0] = v.x; a_[r][1] = v.y; a_[r][2] = v.z; a_[r][3] = v.w;
    }
    __syncthreads();  // wsm free (previous head's GEMM2 done)
#pragma unroll
    for (int u = 0; u < 4; ++u) {
      int idx = t + u * 256, rw = idx >> 4, f4 = idx & 15;
      *(float4*)&wsm[rw][f4 * 4] =
          *(const float4*)(W1 + (size_t)rw * 256 + (hbase + h) * 64 + f4 * 4);
    }
    __syncthreads();

    // GEMM1: t1[r][c'] = sum_k A[row0+r][k] * W1[k][col j*4+c']
    float t1[4][4] = {{0.f,0.f,0.f,0.f},{0.f,0.f,0.f,0.f},{0.f,0.f,0.f,0.f},{0.f,0.f,0.f,0.f}};
#pragma unroll
    for (int kk = 0; kk < 16; ++kk) {
      int srcl = (lane & 48) | kk;
#pragma unroll
      for (int c = 0; c < 4; ++c) {
        float av0 = __shfl(a_[0][c], srcl, 64);
        float av1 = __shfl(a_[1][c], srcl, 64);
        float av2 = __shfl(a_[2][c], srcl, 64);
        float av3 = __shfl(a_[3][c], srcl, 64);
        float4 bv = *(const float4*)&wsm[kk * 4 + c][j * 4];
        t1[0][0] += av0 * bv.x; t1[0][1] += av0 * bv.y; t1[0][2] += av0 * bv.z; t1[0][3] += av0 * bv.w;
        t1[1][0] += av1 * bv.x; t1[1][1] += av1 * bv.y; t1[1][2] += av1 * bv.z; t1[1][3] += av1 * bv.w;
        t1[2][0] += av2 * bv.x; t1[2][1] += av2 * bv.y; t1[2][2] += av2 * bv.z; t1[2][3] += av2 * bv.w;
        t1[3][0] += av3 * bv.x; t1[3][1] += av3 * bv.y; t1[3][2] += av3 * bv.z; t1[3][3] += av3 * bv.w;
      }
    }
    // ELU in registers
#pragma unroll
    for (int r = 0; r < 4; ++r)
#pragma unroll
      for (int c = 0; c < 4; ++c) {
        float v = t1[r][c];
        t1[r][c] = v > 0.f ? v : expm1f(v);
      }

    __syncthreads();  // wsm free (GEMM1 reads done)
#pragma unroll
    for (int u = 0; u < 4; ++u) {
      int idx = t + u * 256, rw = idx >> 4, f4 = idx & 15;
      *(float4*)&wsm[rw][f4 * 4] =
          *(const float4*)(W2 + (size_t)((hbase + h) * 64 + rw) * 64 + f4 * 4);
    }
    __syncthreads();

    // GEMM2: acc2[r][c'] += sum_k elu[row0+r][k] * W2[k][j*4+c']
#pragma unroll
    for (int kk = 0; kk < 16; ++kk) {
      int srcl = (lane & 48) | kk;
#pragma unroll
      for (int c = 0; c < 4; ++c) {
        float av0 = __shfl(t1[0][c], srcl, 64);
        float av1 = __shfl(t1[1][c], srcl, 64);
        float av2 = __shfl(t1[2][c], srcl, 64);
        float av3 = __shfl(t1[3][c], srcl, 64);
        float4 bv = *(const float4*)&wsm[kk * 4 + c][j * 4];
        acc2[0][0] += av0 * bv.x; acc2[0][1] += av0 * bv.y; acc2[0][2] += av0 * bv.z; acc2[0][3] += av0 * bv.w;
        acc2[1][0] += av1 * bv.x; acc2[1][1] += av1 * bv.y; acc2[1][2] += av1 * bv.z; acc2[1][3] += av1 * bv.w;
        acc2[2][0] += av2 * bv.x; acc2[2][1] += av2 * bv.y; acc2[2][2] += av2 * bv.z; acc2[2][3] += av2 * bv.w;
        acc2[3][0] += av3 * bv.x; acc2[3][1] += av3 * bv.y; acc2[3][2] += av3 * bv.z; acc2[3][3] += av3 * bv.w;
      }
    }
  }

  // store h2 tile
#pragma unroll
  for (int r = 0; r < 4; ++r) {
    if (row0 + r < NUM_NODES) {
      float4 o = make_float4(acc2[r][0], acc2[r][1], acc2[r][2], acc2[r][3]);
      *(float4*)(h2 + (size_t)(row0 + r) * 64 + j * 4) = o;
    }
  }

  // fused e2 projections once h2 is complete
  if (last) {
    const float4 alv = *(const float4*)(a2 + j * 4);
    const float4 arv = *(const float4*)(a2 + 64 + j * 4);
#pragma unroll
    for (int r = 0; r < 4; ++r) {
      float ps = acc2[r][0] * alv.x + acc2[r][1] * alv.y + acc2[r][2] * alv.z + acc2[r][3] * alv.w;
      float pd = acc2[r][0] * arv.x + acc2[r][1] * arv.y + acc2[r][2] * arv.z + acc2[r][3] * arv.w;
#pragma unroll
      for (int off = 1; off < 16; off <<= 1) {
        ps += __shfl_xor(ps, off, 64);
        pd += __shfl_xor(pd, off, 64);
      }
      if (j == 0 && row0 + r < NUM_NODES) {
        e2s[row0 + r] = ps;
        e2d[row0 + r] = pd;
      }
    }
  }
}

// ---------------- layer-2 aggregation + residual (flagged nodes only) ----------------
__global__ __launch_bounds__(256) void agg2_kernel(
    const int* __restrict__ offsets, const int* __restrict__ srcs,
    const float* __restrict__ e2s, const float* __restrict__ e2d,
    const int* __restrict__ flags, const float* __restrict__ h2,
    const float* __restrict__ ut, const float* __restrict__ it,
    float* __restrict__ hfin) {
  int wid = threadIdx.x >> 6, lane = threadIdx.x & 63;
  int node = blockIdx.x * 4 + wid;
  if (node >= NUM_NODES) return;
  if (!flags[node]) return;  // output never read for this node
  int beg = offsets[node], end = offsets[node + 1];
  int deg = end - beg;
  float edv = e2d[node];
  float acc = 0.f;

  if (deg <= 64) {
    int s = 0;
    float w = 0.f;
    if (lane < deg) {
      s = srcs[beg + lane];
      float x = e2s[s] + edv;
      x = x > 0.f ? x : 0.2f * x;
      w = __expf(x);
    }
    float sum = w;
#pragma unroll
    for (int off = 32; off; off >>= 1) sum += __shfl_xor(sum, off, 64);
    w *= 1.f / (sum + 1e-8f);
    int e = 0;
    for (; e + 2 <= deg; e += 2) {
      int s0 = __shfl(s, e, 64), s1 = __shfl(s, e + 1, 64);
      float hv0 = h2[(size_t)s0 * 64 + lane];
      float hv1 = h2[(size_t)s1 * 64 + lane];
      acc += __shfl(w, e, 64) * hv0 + __shfl(w, e + 1, 64) * hv1;
    }
    if (e < deg) {
      int s0 = __shfl(s, e, 64);
      acc += __shfl(w, e, 64) * h2[(size_t)s0 * 64 + lane];
    }
  } else {
    float psum = 0.f;
    for (int e = beg + lane; e < end; e += 64) {
      int s = srcs[e];
      float x = e2s[s] + edv;
      x = x > 0.f ? x : 0.2f * x;
      psum += __expf(x);
    }
#pragma unroll
    for (int off = 32; off; off >>= 1) psum += __shfl_xor(psum, off, 64);
    float inv = 1.f / (psum + 1e-8f);
    for (int e = beg; e < end; ++e) {
      int s0 = srcs[e];
      float x0 = e2s[s0] + edv;
      x0 = x0 > 0.f ? x0 : 0.2f * x0;
      acc += __expf(x0) * inv * h2[(size_t)s0 * 64 + lane];
    }
  }
  float res = (node < NUM_USERS) ? ut[(size_t)node * 64 + lane]
                                 : it[(size_t)(node - NUM_USERS) * 64 + lane];
  hfin[(size_t)node * 64 + lane] = acc + res;
}

// ---------------- final batched dot ----------------
__global__ __launch_bounds__(256) void final_kernel(
    const float* __restrict__ hf, const int* __restrict__ uid,
    const int* __restrict__ iid, float* __restrict__ out) {
  int wid = threadIdx.x >> 6, lane = threadIdx.x & 63;
  int idx = blockIdx.x * 4 + wid;
  if (idx >= BATCH) return;
  int u = uid[idx], v = iid[idx];
  float a = hf[(size_t)u * 64 + lane];
  float b = hf[(size_t)(NUM_USERS + v) * 64 + lane];
  float p = a * b;
#pragma unroll
  for (int off = 32; off; off >>= 1) p += __shfl_xor(p, off, 64);
  if (lane == 0) out[idx] = p;
}

extern "C" void kernel_launch(void* const* d_in, const int* in_sizes, int n_in,
                              void* d_out, int out_size, void* d_ws, size_t ws_size,
                              hipStream_t stream) {
  const float* user_table = (const float*)d_in[0];
  const float* item_table = (const float*)d_in[1];
  const float* W1 = (const float*)d_in[2];
  const float* a1 = (const float*)d_in[3];
  const float* W2 = (const float*)d_in[4];
  const float* a2 = (const float*)d_in[5];
  const int* edge_index = (const int*)d_in[6];
  const int* user_ids = (const int*)d_in[7];
  const int* item_ids = (const int*)d_in[8];
  float* out = (float*)d_out;

  const int* src = edge_index;
  const int* dst = edge_index + NUM_EDGES;

  // ---- workspace layout (elements), aggX sized by ws_size ----
  float* ws = (float*)d_ws;
  size_t off = 0;
  auto falloc = [&](size_t n) { float* p = ws + off; off += n; return p; };
  float* h2  = falloc((size_t)NUM_NODES * 64);
  float* e1s = falloc((size_t)NUM_NODES * 4);
  float* e1d = falloc((size_t)NUM_NODES * 4);
  float* e2s = falloc(NUM_NODES);
  float* e2d = falloc(NUM_NODES);
  float* w1a = falloc(256);
  float* w1b = falloc(256);
  int* count   = (int*)falloc(NUM_NODES);
  int* offsets = (int*)falloc(NUM_NODES + 1);
  int* cursor  = (int*)falloc(NUM_NODES);
  int* srcs    = (int*)falloc(NUM_EDGES);
  int* flags   = (int*)falloc(NUM_NODES);
  off = (off + 3) & ~(size_t)3;  // 16B-align aggX for float4 access
  float* aggX = ws + off;
  size_t availElems = (ws_size / 4 > off) ? (ws_size / 4 - off) : 0;

  // head-chunk size: 4 heads in one edge pass if aggX fits, else 2, else 1
  int HC = 1;
  if (availElems >= (size_t)NUM_NODES * 256) HC = 4;
  else if (availElems >= (size_t)NUM_NODES * 128) HC = 2;
  float* hfin = aggX;  // alias: aggX dead after last trans pass

  const int eb = (NUM_EDGES + 255) / 256;
  const int nb4 = (NUM_NODES + 3) / 4;
  const int nb64 = (NUM_NODES + 63) / 64;

  zero_kernel<<<(NUM_NODES + 255) / 256, 256, 0, stream>>>(count, flags);
  flag_kernel<<<(BATCH + 255) / 256, 256, 0, stream>>>(user_ids, item_ids, flags);
  hist_kernel<<<eb, 256, 0, stream>>>(dst, count);
  scan_kernel<<<1, 1024, 0, stream>>>(count, offsets, cursor);
  scatter_kernel<<<eb, 256, 0, stream>>>(src, dst, cursor, srcs);

  proj1_kernel<<<1, 256, 0, stream>>>(W1, a1, w1a, w1b);
  e1_kernel<<<nb4, 256, 0, stream>>>(user_table, item_table, w1a, w1b, e1s, e1d);

  for (int hbase = 0; hbase < 4; hbase += HC) {
    int last = (hbase + HC == 4) ? 1 : 0;
    switch (HC) {
      case 4:
        aggX_kernel<4><<<nb4, 256, 0, stream>>>(offsets, srcs, e1s, e1d,
                                                user_table, item_table, hbase, aggX);
        trans_kernel<4><<<nb64, 256, 0, stream>>>(aggX, W1, W2, a2, hbase, last,
                                                  h2, e2s, e2d);
        break;
      case 2:
        aggX_kernel<2><<<nb4, 256, 0, stream>>>(offsets, srcs, e1s, e1d,
                                                user_table, item_table, hbase, aggX);
        trans_kernel<2><<<nb64, 256, 0, stream>>>(aggX, W1, W2, a2, hbase, last,
                                                  h2, e2s, e2d);
        break;
      default:
        aggX_kernel<1><<<nb4, 256, 0, stream>>>(offsets, srcs, e1s, e1d,
                                                user_table, item_table, hbase, aggX);
        trans_kernel<1><<<nb64, 256, 0, stream>>>(aggX, W1, W2, a2, hbase, last,
                                                  h2, e2s, e2d);
        break;
    }
  }

  agg2_kernel<<<nb4, 256, 0, stream>>>(offsets, srcs, e2s, e2d, flags,
                                       h2, user_table, item_table, hfin);
  final_kernel<<<(BATCH + 3) / 4, 256, 0, stream>>>(hfin, user_ids, item_ids, out);
}

// Round 5
// 1069.091 us; speedup vs baseline: 3.2842x; 1.6225x over previous
//
#include <hip/hip_runtime.h>
#include <cstdint>
#include <cstddef>

#define NUM_USERS 100000
#define NUM_ITEMS 50000
#define NUM_NODES 150000
#define NUM_EDGES 2000000
#define BATCH 16384

// ---------------- init (no hipMemsetAsync anywhere) ----------------
__global__ void zero_kernel(int* __restrict__ count, int* __restrict__ flags) {
  int i = blockIdx.x * blockDim.x + threadIdx.x;
  if (i < NUM_NODES) { count[i] = 0; flags[i] = 0; }
}

__global__ void flag_kernel(const int* __restrict__ uid, const int* __restrict__ iid,
                            int* __restrict__ flags) {
  int i = blockIdx.x * blockDim.x + threadIdx.x;
  if (i < BATCH) {
    flags[uid[i]] = 1;
    flags[NUM_USERS + iid[i]] = 1;
  }
}

// ---------------- CSR construction ----------------
__global__ void hist_kernel(const int* __restrict__ dst, int* __restrict__ count) {
  int e = blockIdx.x * blockDim.x + threadIdx.x;
  if (e < NUM_EDGES) atomicAdd(&count[dst[e]], 1);
}

__global__ void scan_kernel(const int* __restrict__ count, int* __restrict__ offsets,
                            int* __restrict__ cursor) {
  __shared__ int ssum[1024];
  const int n = NUM_NODES;
  int t = threadIdx.x;
  const int chunk = (n + 1023) >> 10;
  int b = t * chunk;
  int e = b + chunk; if (e > n) e = n;
  if (b > n) b = n;
  int s = 0;
  for (int i = b; i < e; ++i) s += count[i];
  ssum[t] = s;
  __syncthreads();
  for (int off = 1; off < 1024; off <<= 1) {
    int v = 0;
    if (t >= off) v = ssum[t - off];
    __syncthreads();
    if (t >= off) ssum[t] += v;
    __syncthreads();
  }
  int run = (t == 0) ? 0 : ssum[t - 1];
  for (int i = b; i < e; ++i) {
    offsets[i] = run;
    cursor[i] = run;
    run += count[i];
  }
  if (t == 1023) offsets[n] = ssum[1023];  // == NUM_EDGES
}

__global__ void scatter_kernel(const int* __restrict__ src, const int* __restrict__ dst,
                               int* __restrict__ cursor, int* __restrict__ src_sorted) {
  int e = blockIdx.x * blockDim.x + threadIdx.x;
  if (e < NUM_EDGES) {
    int p = atomicAdd(&cursor[dst[e]], 1);
    src_sorted[p] = src[e];
  }
}

// ---------------- projected attention vectors: w1a[h][k] = sum_f W1[k, h*64+f]*a_l[h,f]
__global__ void proj1_kernel(const float* __restrict__ W1, const float* __restrict__ a1,
                             float* __restrict__ w1a, float* __restrict__ w1b) {
  int t = threadIdx.x;  // 256 threads: h = t>>6, k = t&63
  int h = t >> 6, k = t & 63;
  float sa = 0.f, sb = 0.f;
  for (int f = 0; f < 64; ++f) {
    float w = W1[(size_t)k * 256 + h * 64 + f];
    sa += w * a1[h * 128 + f];
    sb += w * a1[h * 128 + 64 + f];
  }
  w1a[h * 64 + k] = sa;
  w1b[h * 64 + k] = sb;
}

// ---------------- e1 tables straight from embeddings ----------------
__global__ __launch_bounds__(256) void e1_kernel(
    const float* __restrict__ ut, const float* __restrict__ it,
    const float* __restrict__ w1a, const float* __restrict__ w1b,
    float* __restrict__ e1s, float* __restrict__ e1d) {
  int wid = threadIdx.x >> 6, lane = threadIdx.x & 63;
  int node = blockIdx.x * 4 + wid;
  if (node >= NUM_NODES) return;
  const float* x = (node < NUM_USERS) ? ut + (size_t)node * 64
                                      : it + (size_t)(node - NUM_USERS) * 64;
  float xv = x[lane];
#pragma unroll
  for (int h = 0; h < 4; ++h) {
    float ps = xv * w1a[h * 64 + lane];
    float pd = xv * w1b[h * 64 + lane];
#pragma unroll
    for (int off = 32; off; off >>= 1) {
      ps += __shfl_xor(ps, off, 64);
      pd += __shfl_xor(pd, off, 64);
    }
    if (lane == 0) {
      e1s[(size_t)node * 4 + h] = ps;
      e1d[(size_t)node * 4 + h] = pd;
    }
  }
}

// ---- vector load of HC consecutive e-table entries for node s ----
template <int HC>
__device__ __forceinline__ void ld_e(const float* __restrict__ e, int s, int hbase,
                                     float out[HC]) {
  if constexpr (HC == 4) {
    float4 v = *(const float4*)(e + (size_t)s * 4);
    out[0] = v.x; out[1] = v.y; out[2] = v.z; out[3] = v.w;
  } else if constexpr (HC == 2) {
    float2 v = *(const float2*)(e + (size_t)s * 4 + hbase);
    out[0] = v.x; out[1] = v.y;
  } else {
    out[0] = e[(size_t)s * 4 + hbase];
  }
}

__device__ __forceinline__ const float* row_ptr(int s, const float* __restrict__ ut,
                                                const float* __restrict__ it) {
  return (s < NUM_USERS) ? ut + (size_t)s * 64 : it + (size_t)(s - NUM_USERS) * 64;
}

// ---------------- edge pass: attention-weighted aggregation of RAW embeddings ----------------
// aggX[node][h*64+f] = sum_e softmax_att(h,e) * X[src_e][f]   (heads hbase..hbase+HC-1)
// Softmax computed WITHOUT max-shift: logits are O(0.3) (xavier dots), exp is safe,
// and softmax is shift-invariant (epsilon perturbation ~2e-10 relative).
template <int HC>
__global__ __launch_bounds__(256) void aggX_kernel(
    const int* __restrict__ offsets, const int* __restrict__ srcs,
    const float* __restrict__ e1s, const float* __restrict__ e1d,
    const float* __restrict__ ut, const float* __restrict__ it,
    int hbase, float* __restrict__ aggX) {
  int wid = threadIdx.x >> 6, lane = threadIdx.x & 63;
  int node = blockIdx.x * 4 + wid;
  if (node >= NUM_NODES) return;
  int beg = offsets[node], end = offsets[node + 1];
  int deg = end - beg;
  float edv[HC];
#pragma unroll
  for (int h = 0; h < HC; ++h) edv[h] = e1d[(size_t)node * 4 + hbase + h];

  float acc[HC];
#pragma unroll
  for (int h = 0; h < HC; ++h) acc[h] = 0.f;

  if (deg <= 64) {
    // ---- fast path: cache src ids + normalized weights in registers ----
    int s = 0;
    float w[HC];
#pragma unroll
    for (int h = 0; h < HC; ++h) w[h] = 0.f;
    if (lane < deg) {
      s = srcs[beg + lane];
      float ev[HC];
      ld_e<HC>(e1s, s, hbase, ev);
#pragma unroll
      for (int h = 0; h < HC; ++h) {
        float x = ev[h] + edv[h];
        x = x > 0.f ? x : 0.2f * x;
        w[h] = __expf(x);
      }
    }
#pragma unroll
    for (int h = 0; h < HC; ++h) {
      float sum = w[h];
#pragma unroll
      for (int off = 32; off; off >>= 1) sum += __shfl_xor(sum, off, 64);
      w[h] *= 1.f / (sum + 1e-8f);
    }
    // edge walk: 4 independent row gathers in flight (no loads in dependent chain)
    int e = 0;
    for (; e + 4 <= deg; e += 4) {
      int s0 = __shfl(s, e, 64), s1 = __shfl(s, e + 1, 64);
      int s2 = __shfl(s, e + 2, 64), s3 = __shfl(s, e + 3, 64);
      float xv0 = row_ptr(s0, ut, it)[lane];
      float xv1 = row_ptr(s1, ut, it)[lane];
      float xv2 = row_ptr(s2, ut, it)[lane];
      float xv3 = row_ptr(s3, ut, it)[lane];
#pragma unroll
      for (int h = 0; h < HC; ++h) {
        acc[h] += __shfl(w[h], e, 64) * xv0 + __shfl(w[h], e + 1, 64) * xv1 +
                  __shfl(w[h], e + 2, 64) * xv2 + __shfl(w[h], e + 3, 64) * xv3;
      }
    }
    for (; e < deg; ++e) {
      int s0 = __shfl(s, e, 64);
      float xv0 = row_ptr(s0, ut, it)[lane];
#pragma unroll
      for (int h = 0; h < HC; ++h) acc[h] += __shfl(w[h], e, 64) * xv0;
    }
  } else {
    // ---- generic fallback (deg > 64): two streaming passes ----
    float sums[HC];
#pragma unroll
    for (int h = 0; h < HC; ++h) sums[h] = 0.f;
    for (int e = beg + lane; e < end; e += 64) {
      int s = srcs[e];
      float ev[HC];
      ld_e<HC>(e1s, s, hbase, ev);
#pragma unroll
      for (int h = 0; h < HC; ++h) {
        float x = ev[h] + edv[h];
        x = x > 0.f ? x : 0.2f * x;
        sums[h] += __expf(x);
      }
    }
#pragma unroll
    for (int h = 0; h < HC; ++h) {
#pragma unroll
      for (int off = 32; off; off >>= 1) sums[h] += __shfl_xor(sums[h], off, 64);
    }
    float inv[HC];
#pragma unroll
    for (int h = 0; h < HC; ++h) inv[h] = 1.f / (sums[h] + 1e-8f);
    for (int e = beg; e < end; ++e) {
      int s0 = srcs[e];
      float ev0[HC];
      ld_e<HC>(e1s, s0, hbase, ev0);
      float xv0 = row_ptr(s0, ut, it)[lane];
#pragma unroll
      for (int h = 0; h < HC; ++h) {
        float x0 = ev0[h] + edv[h];
        x0 = x0 > 0.f ? x0 : 0.2f * x0;
        acc[h] += __expf(x0) * inv[h] * xv0;
      }
    }
  }
#pragma unroll
  for (int h = 0; h < HC; ++h)
    aggX[(size_t)node * (HC * 64) + h * 64 + lane] = acc[h];
}

// ---------------- dense transform: h2 += elu(aggX_h @ W1_h) @ W2_h ----------------
// Row-major LDS tiles only (pad 68 keeps float4 alignment; all accesses at or
// near the b128 bandwidth floor — no transpose anywhere: the ELU intermediate
// is written row-major and re-read with the same pattern). Fused e2 on last.
template <int HC>
__global__ __launch_bounds__(256, 3) void trans_kernel(
    const float* __restrict__ aggX, const float* __restrict__ W1,
    const float* __restrict__ W2, const float* __restrict__ a2,
    int hbase, int last, float* __restrict__ h2,
    float* __restrict__ e2s, float* __restrict__ e2d) {
  __shared__ __align__(16) float xs[64][68];   // A rows (row-major, k contiguous)
  __shared__ __align__(16) float wsm[64][68];  // W rows
  const int t = threadIdx.x;
  const int rb = blockIdx.x;
  const int j = t & 15, i = t >> 4;
  const int row0 = rb * 64;

  float acc2[4][4];
#pragma unroll
  for (int r = 0; r < 4; ++r) { acc2[r][0] = 0.f; acc2[r][1] = 0.f; acc2[r][2] = 0.f; acc2[r][3] = 0.f; }
  if (hbase != 0) {
#pragma unroll
    for (int r = 0; r < 4; ++r) {
      int grow = row0 + i * 4 + r;
      if (grow < NUM_NODES) {
        float4 v = *(const float4*)(h2 + (size_t)grow * 64 + j * 4);
        acc2[r][0] = v.x; acc2[r][1] = v.y; acc2[r][2] = v.z; acc2[r][3] = v.w;
      }
    }
  }

#pragma unroll 1
  for (int h = 0; h < HC; ++h) {
    __syncthreads();  // previous head's GEMM2 reads complete
    // stage A tile (row-major) + W1 head slice
#pragma unroll
    for (int u = 0; u < 4; ++u) {
      int idx = t + u * 256, rw = idx >> 4, f4 = idx & 15;
      int grow = row0 + rw;
      float4 v = make_float4(0.f, 0.f, 0.f, 0.f);
      if (grow < NUM_NODES)
        v = *(const float4*)(aggX + (size_t)grow * (HC * 64) + h * 64 + f4 * 4);
      *(float4*)&xs[rw][f4 * 4] = v;
      *(float4*)&wsm[rw][f4 * 4] =
          *(const float4*)(W1 + (size_t)rw * 256 + (hbase + h) * 64 + f4 * 4);
    }
    __syncthreads();

    // GEMM1: t1[r][cc] = sum_k A[i4+r][k] * W1[k][j4+cc]
    float t1[4][4] = {{0.f,0.f,0.f,0.f},{0.f,0.f,0.f,0.f},{0.f,0.f,0.f,0.f},{0.f,0.f,0.f,0.f}};
#pragma unroll 2
    for (int k4 = 0; k4 < 16; ++k4) {
      float4 a0 = *(const float4*)&xs[i * 4 + 0][k4 * 4];
      float4 a1_ = *(const float4*)&xs[i * 4 + 1][k4 * 4];
      float4 a2_ = *(const float4*)&xs[i * 4 + 2][k4 * 4];
      float4 a3 = *(const float4*)&xs[i * 4 + 3][k4 * 4];
#pragma unroll
      for (int c = 0; c < 4; ++c) {
        float4 bv = *(const float4*)&wsm[k4 * 4 + c][j * 4];
        float av0 = (&a0.x)[c], av1 = (&a1_.x)[c], av2 = (&a2_.x)[c], av3 = (&a3.x)[c];
        t1[0][0] += av0 * bv.x; t1[0][1] += av0 * bv.y; t1[0][2] += av0 * bv.z; t1[0][3] += av0 * bv.w;
        t1[1][0] += av1 * bv.x; t1[1][1] += av1 * bv.y; t1[1][2] += av1 * bv.z; t1[1][3] += av1 * bv.w;
        t1[2][0] += av2 * bv.x; t1[2][1] += av2 * bv.y; t1[2][2] += av2 * bv.z; t1[2][3] += av2 * bv.w;
        t1[3][0] += av3 * bv.x; t1[3][1] += av3 * bv.y; t1[3][2] += av3 * bv.z; t1[3][3] += av3 * bv.w;
      }
    }
    __syncthreads();  // GEMM1 LDS reads complete before overwrite

    // ELU + write back row-major (same layout → GEMM2 reads like GEMM1; no transpose)
#pragma unroll
    for (int r = 0; r < 4; ++r) {
      float4 o;
      o.x = t1[r][0] > 0.f ? t1[r][0] : expm1f(t1[r][0]);
      o.y = t1[r][1] > 0.f ? t1[r][1] : expm1f(t1[r][1]);
      o.z = t1[r][2] > 0.f ? t1[r][2] : expm1f(t1[r][2]);
      o.w = t1[r][3] > 0.f ? t1[r][3] : expm1f(t1[r][3]);
      *(float4*)&xs[i * 4 + r][j * 4] = o;
    }
#pragma unroll
    for (int u = 0; u < 4; ++u) {
      int idx = t + u * 256, rw = idx >> 4, f4 = idx & 15;
      *(float4*)&wsm[rw][f4 * 4] =
          *(const float4*)(W2 + (size_t)((hbase + h) * 64 + rw) * 64 + f4 * 4);
    }
    __syncthreads();

    // GEMM2: acc2[r][cc] += sum_k elu[i4+r][k] * W2[k][j4+cc]
#pragma unroll 2
    for (int k4 = 0; k4 < 16; ++k4) {
      float4 a0 = *(const float4*)&xs[i * 4 + 0][k4 * 4];
      float4 a1_ = *(const float4*)&xs[i * 4 + 1][k4 * 4];
      float4 a2_ = *(const float4*)&xs[i * 4 + 2][k4 * 4];
      float4 a3 = *(const float4*)&xs[i * 4 + 3][k4 * 4];
#pragma unroll
      for (int c = 0; c < 4; ++c) {
        float4 bv = *(const float4*)&wsm[k4 * 4 + c][j * 4];
        float av0 = (&a0.x)[c], av1 = (&a1_.x)[c], av2 = (&a2_.x)[c], av3 = (&a3.x)[c];
        acc2[0][0] += av0 * bv.x; acc2[0][1] += av0 * bv.y; acc2[0][2] += av0 * bv.z; acc2[0][3] += av0 * bv.w;
        acc2[1][0] += av1 * bv.x; acc2[1][1] += av1 * bv.y; acc2[1][2] += av1 * bv.z; acc2[1][3] += av1 * bv.w;
        acc2[2][0] += av2 * bv.x; acc2[2][1] += av2 * bv.y; acc2[2][2] += av2 * bv.z; acc2[2][3] += av2 * bv.w;
        acc2[3][0] += av3 * bv.x; acc2[3][1] += av3 * bv.y; acc2[3][2] += av3 * bv.z; acc2[3][3] += av3 * bv.w;
      }
    }
  }

  // store h2 tile
#pragma unroll
  for (int r = 0; r < 4; ++r) {
    int grow = row0 + i * 4 + r;
    if (grow < NUM_NODES) {
      float4 o = make_float4(acc2[r][0], acc2[r][1], acc2[r][2], acc2[r][3]);
      *(float4*)(h2 + (size_t)grow * 64 + j * 4) = o;
    }
  }

  // fused e2 projections once h2 is complete
  if (last) {
    const float4 alv = *(const float4*)(a2 + j * 4);
    const float4 arv = *(const float4*)(a2 + 64 + j * 4);
#pragma unroll
    for (int r = 0; r < 4; ++r) {
      float ps = acc2[r][0] * alv.x + acc2[r][1] * alv.y + acc2[r][2] * alv.z + acc2[r][3] * alv.w;
      float pd = acc2[r][0] * arv.x + acc2[r][1] * arv.y + acc2[r][2] * arv.z + acc2[r][3] * arv.w;
#pragma unroll
      for (int off = 1; off < 16; off <<= 1) {
        ps += __shfl_xor(ps, off, 64);
        pd += __shfl_xor(pd, off, 64);
      }
      if (j == 0) {
        int grow = row0 + i * 4 + r;
        if (grow < NUM_NODES) { e2s[grow] = ps; e2d[grow] = pd; }
      }
    }
  }
}

// ---------------- layer-2 aggregation + residual (flagged nodes only) ----------------
__global__ __launch_bounds__(256) void agg2_kernel(
    const int* __restrict__ offsets, const int* __restrict__ srcs,
    const float* __restrict__ e2s, const float* __restrict__ e2d,
    const int* __restrict__ flags, const float* __restrict__ h2,
    const float* __restrict__ ut, const float* __restrict__ it,
    float* __restrict__ hfin) {
  int wid = threadIdx.x >> 6, lane = threadIdx.x & 63;
  int node = blockIdx.x * 4 + wid;
  if (node >= NUM_NODES) return;
  if (!flags[node]) return;  // output never read for this node
  int beg = offsets[node], end = offsets[node + 1];
  int deg = end - beg;
  float edv = e2d[node];
  float acc = 0.f;

  if (deg <= 64) {
    int s = 0;
    float w = 0.f;
    if (lane < deg) {
      s = srcs[beg + lane];
      float x = e2s[s] + edv;
      x = x > 0.f ? x : 0.2f * x;
      w = __expf(x);
    }
    float sum = w;
#pragma unroll
    for (int off = 32; off; off >>= 1) sum += __shfl_xor(sum, off, 64);
    w *= 1.f / (sum + 1e-8f);
    int e = 0;
    for (; e + 4 <= deg; e += 4) {
      int s0 = __shfl(s, e, 64), s1 = __shfl(s, e + 1, 64);
      int s2 = __shfl(s, e + 2, 64), s3 = __shfl(s, e + 3, 64);
      float hv0 = h2[(size_t)s0 * 64 + lane];
      float hv1 = h2[(size_t)s1 * 64 + lane];
      float hv2 = h2[(size_t)s2 * 64 + lane];
      float hv3 = h2[(size_t)s3 * 64 + lane];
      acc += __shfl(w, e, 64) * hv0 + __shfl(w, e + 1, 64) * hv1 +
             __shfl(w, e + 2, 64) * hv2 + __shfl(w, e + 3, 64) * hv3;
    }
    for (; e < deg; ++e) {
      int s0 = __shfl(s, e, 64);
      acc += __shfl(w, e, 64) * h2[(size_t)s0 * 64 + lane];
    }
  } else {
    float psum = 0.f;
    for (int e = beg + lane; e < end; e += 64) {
      int s = srcs[e];
      float x = e2s[s] + edv;
      x = x > 0.f ? x : 0.2f * x;
      psum += __expf(x);
    }
#pragma unroll
    for (int off = 32; off; off >>= 1) psum += __shfl_xor(psum, off, 64);
    float inv = 1.f / (psum + 1e-8f);
    for (int e = beg; e < end; ++e) {
      int s0 = srcs[e];
      float x0 = e2s[s0] + edv;
      x0 = x0 > 0.f ? x0 : 0.2f * x0;
      acc += __expf(x0) * inv * h2[(size_t)s0 * 64 + lane];
    }
  }
  float res = (node < NUM_USERS) ? ut[(size_t)node * 64 + lane]
                                 : it[(size_t)(node - NUM_USERS) * 64 + lane];
  hfin[(size_t)node * 64 + lane] = acc + res;
}

// ---------------- final batched dot ----------------
__global__ __launch_bounds__(256) void final_kernel(
    const float* __restrict__ hf, const int* __restrict__ uid,
    const int* __restrict__ iid, float* __restrict__ out) {
  int wid = threadIdx.x >> 6, lane = threadIdx.x & 63;
  int idx = blockIdx.x * 4 + wid;
  if (idx >= BATCH) return;
  int u = uid[idx], v = iid[idx];
  float a = hf[(size_t)u * 64 + lane];
  float b = hf[(size_t)(NUM_USERS + v) * 64 + lane];
  float p = a * b;
#pragma unroll
  for (int off = 32; off; off >>= 1) p += __shfl_xor(p, off, 64);
  if (lane == 0) out[idx] = p;
}

extern "C" void kernel_launch(void* const* d_in, const int* in_sizes, int n_in,
                              void* d_out, int out_size, void* d_ws, size_t ws_size,
                              hipStream_t stream) {
  const float* user_table = (const float*)d_in[0];
  const float* item_table = (const float*)d_in[1];
  const float* W1 = (const float*)d_in[2];
  const float* a1 = (const float*)d_in[3];
  const float* W2 = (const float*)d_in[4];
  const float* a2 = (const float*)d_in[5];
  const int* edge_index = (const int*)d_in[6];
  const int* user_ids = (const int*)d_in[7];
  const int* item_ids = (const int*)d_in[8];
  float* out = (float*)d_out;

  const int* src = edge_index;
  const int* dst = edge_index + NUM_EDGES;

  // ---- workspace layout (elements), aggX sized by ws_size ----
  float* ws = (float*)d_ws;
  size_t off = 0;
  auto falloc = [&](size_t n) { float* p = ws + off; off += n; return p; };
  float* h2  = falloc((size_t)NUM_NODES * 64);
  float* e1s = falloc((size_t)NUM_NODES * 4);
  float* e1d = falloc((size_t)NUM_NODES * 4);
  float* e2s = falloc(NUM_NODES);
  float* e2d = falloc(NUM_NODES);
  float* w1a = falloc(256);
  float* w1b = falloc(256);
  int* count   = (int*)falloc(NUM_NODES);
  int* offsets = (int*)falloc(NUM_NODES + 1);
  int* cursor  = (int*)falloc(NUM_NODES);
  int* srcs    = (int*)falloc(NUM_EDGES);
  int* flags   = (int*)falloc(NUM_NODES);
  off = (off + 3) & ~(size_t)3;  // 16B-align aggX for float4 access
  float* aggX = ws + off;
  size_t availElems = (ws_size / 4 > off) ? (ws_size / 4 - off) : 0;

  // head-chunk size: 4 heads in one edge pass if aggX fits, else 2, else 1
  int HC = 1;
  if (availElems >= (size_t)NUM_NODES * 256) HC = 4;
  else if (availElems >= (size_t)NUM_NODES * 128) HC = 2;
  float* hfin = aggX;  // alias: aggX dead after last trans pass

  const int eb = (NUM_EDGES + 255) / 256;
  const int nb4 = (NUM_NODES + 3) / 4;
  const int nb64 = (NUM_NODES + 63) / 64;

  zero_kernel<<<(NUM_NODES + 255) / 256, 256, 0, stream>>>(count, flags);
  flag_kernel<<<(BATCH + 255) / 256, 256, 0, stream>>>(user_ids, item_ids, flags);
  hist_kernel<<<eb, 256, 0, stream>>>(dst, count);
  scan_kernel<<<1, 1024, 0, stream>>>(count, offsets, cursor);
  scatter_kernel<<<eb, 256, 0, stream>>>(src, dst, cursor, srcs);

  proj1_kernel<<<1, 256, 0, stream>>>(W1, a1, w1a, w1b);
  e1_kernel<<<nb4, 256, 0, stream>>>(user_table, item_table, w1a, w1b, e1s, e1d);

  for (int hbase = 0; hbase < 4; hbase += HC) {
    int last = (hbase + HC == 4) ? 1 : 0;
    switch (HC) {
      case 4:
        aggX_kernel<4><<<nb4, 256, 0, stream>>>(offsets, srcs, e1s, e1d,
                                                user_table, item_table, hbase, aggX);
        trans_kernel<4><<<nb64, 256, 0, stream>>>(aggX, W1, W2, a2, hbase, last,
                                                  h2, e2s, e2d);
        break;
      case 2:
        aggX_kernel<2><<<nb4, 256, 0, stream>>>(offsets, srcs, e1s, e1d,
                                                user_table, item_table, hbase, aggX);
        trans_kernel<2><<<nb64, 256, 0, stream>>>(aggX, W1, W2, a2, hbase, last,
                                                  h2, e2s, e2d);
        break;
      default:
        aggX_kernel<1><<<nb4, 256, 0, stream>>>(offsets, srcs, e1s, e1d,
                                                user_table, item_table, hbase, aggX);
        trans_kernel<1><<<nb64, 256, 0, stream>>>(aggX, W1, W2, a2, hbase, last,
                                                  h2, e2s, e2d);
        break;
    }
  }

  agg2_kernel<<<nb4, 256, 0, stream>>>(offsets, srcs, e2s, e2d, flags,
                                       h2, user_table, item_table, hfin);
  final_kernel<<<(BATCH + 3) / 4, 256, 0, stream>>>(hfin, user_ids, item_ids, out);
}

// Round 6
// 751.973 us; speedup vs baseline: 4.6691x; 1.4217x over previous
//
#include <hip/hip_runtime.h>
#include <cstdint>
#include <cstddef>

#define NUM_USERS 100000
#define NUM_ITEMS 50000
#define NUM_NODES 150000
#define NUM_EDGES 2000000
#define BATCH 16384
#define NB_SCAN ((NUM_NODES + 255) / 256)  // 586 scan blocks

// ---------------- init (no hipMemsetAsync anywhere) ----------------
__global__ void zero_kernel(int* __restrict__ count, int* __restrict__ flags) {
  int i = blockIdx.x * blockDim.x + threadIdx.x;
  if (i < NUM_NODES) { count[i] = 0; flags[i] = 0; }
}

__global__ void flag_kernel(const int* __restrict__ uid, const int* __restrict__ iid,
                            int* __restrict__ flags) {
  int i = blockIdx.x * blockDim.x + threadIdx.x;
  if (i < BATCH) {
    flags[uid[i]] = 1;
    flags[NUM_USERS + iid[i]] = 1;
  }
}

// ---------------- CSR construction ----------------
__global__ void hist_kernel(const int* __restrict__ dst, int* __restrict__ count) {
  int e = blockIdx.x * blockDim.x + threadIdx.x;
  if (e < NUM_EDGES) atomicAdd(&count[dst[e]], 1);
}

// 3-kernel decoupled scan (replaces the 337 µs single-CU serial scan)
__global__ void blocksum_kernel(const int* __restrict__ count, int* __restrict__ bsum) {
  __shared__ int sh[256];
  int t = threadIdx.x;
  int i = blockIdx.x * 256 + t;
  sh[t] = (i < NUM_NODES) ? count[i] : 0;
  __syncthreads();
#pragma unroll
  for (int off = 128; off; off >>= 1) {
    if (t < off) sh[t] += sh[t + off];
    __syncthreads();
  }
  if (t == 0) bsum[blockIdx.x] = sh[0];
}

__global__ void scanb_kernel(const int* __restrict__ bsum, int* __restrict__ bpre,
                             int* __restrict__ offsets) {
  __shared__ int sh[1024];
  int t = threadIdx.x;
  int v = (t < NB_SCAN) ? bsum[t] : 0;
  sh[t] = v;
  __syncthreads();
  for (int off = 1; off < 1024; off <<= 1) {
    int x = (t >= off) ? sh[t - off] : 0;
    __syncthreads();
    sh[t] += x;
    __syncthreads();
  }
  if (t < NB_SCAN) bpre[t] = sh[t] - v;
  if (t == NB_SCAN - 1) offsets[NUM_NODES] = sh[t];  // total == NUM_EDGES
}

__global__ void scanf_kernel(const int* __restrict__ count, const int* __restrict__ bpre,
                             int* __restrict__ offsets, int* __restrict__ cursor) {
  __shared__ int sh[256];
  int t = threadIdx.x;
  int i = blockIdx.x * 256 + t;
  int v = (i < NUM_NODES) ? count[i] : 0;
  sh[t] = v;
  __syncthreads();
  for (int off = 1; off < 256; off <<= 1) {
    int x = (t >= off) ? sh[t - off] : 0;
    __syncthreads();
    sh[t] += x;
    __syncthreads();
  }
  if (i < NUM_NODES) {
    int excl = bpre[blockIdx.x] + sh[t] - v;
    offsets[i] = excl;
    cursor[i] = excl;
  }
}

__global__ void scatter_kernel(const int* __restrict__ src, const int* __restrict__ dst,
                               int* __restrict__ cursor, int* __restrict__ src_sorted) {
  int e = blockIdx.x * blockDim.x + threadIdx.x;
  if (e < NUM_EDGES) {
    int p = atomicAdd(&cursor[dst[e]], 1);
    src_sorted[p] = src[e];
  }
}

// ---------------- projected attention vectors: w1a[h][k] = sum_f W1[k, h*64+f]*a_l[h,f]
__global__ void proj1_kernel(const float* __restrict__ W1, const float* __restrict__ a1,
                             float* __restrict__ w1a, float* __restrict__ w1b) {
  int t = threadIdx.x;  // 256 threads: h = t>>6, k = t&63
  int h = t >> 6, k = t & 63;
  float sa = 0.f, sb = 0.f;
  for (int f = 0; f < 64; ++f) {
    float w = W1[(size_t)k * 256 + h * 64 + f];
    sa += w * a1[h * 128 + f];
    sb += w * a1[h * 128 + 64 + f];
  }
  w1a[h * 64 + k] = sa;
  w1b[h * 64 + k] = sb;
}

// ---------------- e1 tables straight from embeddings ----------------
__global__ __launch_bounds__(256) void e1_kernel(
    const float* __restrict__ ut, const float* __restrict__ it,
    const float* __restrict__ w1a, const float* __restrict__ w1b,
    float* __restrict__ e1s, float* __restrict__ e1d) {
  int wid = threadIdx.x >> 6, lane = threadIdx.x & 63;
  int node = blockIdx.x * 4 + wid;
  if (node >= NUM_NODES) return;
  const float* x = (node < NUM_USERS) ? ut + (size_t)node * 64
                                      : it + (size_t)(node - NUM_USERS) * 64;
  float xv = x[lane];
#pragma unroll
  for (int h = 0; h < 4; ++h) {
    float ps = xv * w1a[h * 64 + lane];
    float pd = xv * w1b[h * 64 + lane];
#pragma unroll
    for (int off = 32; off; off >>= 1) {
      ps += __shfl_xor(ps, off, 64);
      pd += __shfl_xor(pd, off, 64);
    }
    if (lane == 0) {
      e1s[(size_t)node * 4 + h] = ps;
      e1d[(size_t)node * 4 + h] = pd;
    }
  }
}

// ---- vector load of HC consecutive e-table entries for node s ----
template <int HC>
__device__ __forceinline__ void ld_e(const float* __restrict__ e, int s, int hbase,
                                     float out[HC]) {
  if constexpr (HC == 4) {
    float4 v = *(const float4*)(e + (size_t)s * 4);
    out[0] = v.x; out[1] = v.y; out[2] = v.z; out[3] = v.w;
  } else if constexpr (HC == 2) {
    float2 v = *(const float2*)(e + (size_t)s * 4 + hbase);
    out[0] = v.x; out[1] = v.y;
  } else {
    out[0] = e[(size_t)s * 4 + hbase];
  }
}

__device__ __forceinline__ const float* row_ptr(int s, const float* __restrict__ ut,
                                                const float* __restrict__ it) {
  return (s < NUM_USERS) ? ut + (size_t)s * 64 : it + (size_t)(s - NUM_USERS) * 64;
}

// ---------------- edge pass: attention-weighted aggregation of RAW embeddings ----------------
// aggX[node][h*64+f] = sum_e softmax_att(h,e) * X[src_e][f]   (heads hbase..hbase+HC-1)
// Softmax computed WITHOUT max-shift: logits are O(0.3) (xavier dots), exp is safe,
// and softmax is shift-invariant (epsilon perturbation ~2e-10 relative).
template <int HC>
__global__ __launch_bounds__(256) void aggX_kernel(
    const int* __restrict__ offsets, const int* __restrict__ srcs,
    const float* __restrict__ e1s, const float* __restrict__ e1d,
    const float* __restrict__ ut, const float* __restrict__ it,
    int hbase, float* __restrict__ aggX) {
  int wid = threadIdx.x >> 6, lane = threadIdx.x & 63;
  int node = blockIdx.x * 4 + wid;
  if (node >= NUM_NODES) return;
  int beg = offsets[node], end = offsets[node + 1];
  int deg = end - beg;
  float edv[HC];
#pragma unroll
  for (int h = 0; h < HC; ++h) edv[h] = e1d[(size_t)node * 4 + hbase + h];

  float acc[HC];
#pragma unroll
  for (int h = 0; h < HC; ++h) acc[h] = 0.f;

  if (deg <= 64) {
    // ---- fast path: cache src ids + normalized weights in registers ----
    int s = 0;
    float w[HC];
#pragma unroll
    for (int h = 0; h < HC; ++h) w[h] = 0.f;
    if (lane < deg) {
      s = srcs[beg + lane];
      float ev[HC];
      ld_e<HC>(e1s, s, hbase, ev);
#pragma unroll
      for (int h = 0; h < HC; ++h) {
        float x = ev[h] + edv[h];
        x = x > 0.f ? x : 0.2f * x;
        w[h] = __expf(x);
      }
    }
#pragma unroll
    for (int h = 0; h < HC; ++h) {
      float sum = w[h];
#pragma unroll
      for (int off = 32; off; off >>= 1) sum += __shfl_xor(sum, off, 64);
      w[h] *= 1.f / (sum + 1e-8f);
    }
    // edge walk: 4 independent row gathers in flight (no loads in dependent chain)
    int e = 0;
    for (; e + 4 <= deg; e += 4) {
      int s0 = __shfl(s, e, 64), s1 = __shfl(s, e + 1, 64);
      int s2 = __shfl(s, e + 2, 64), s3 = __shfl(s, e + 3, 64);
      float xv0 = row_ptr(s0, ut, it)[lane];
      float xv1 = row_ptr(s1, ut, it)[lane];
      float xv2 = row_ptr(s2, ut, it)[lane];
      float xv3 = row_ptr(s3, ut, it)[lane];
#pragma unroll
      for (int h = 0; h < HC; ++h) {
        acc[h] += __shfl(w[h], e, 64) * xv0 + __shfl(w[h], e + 1, 64) * xv1 +
                  __shfl(w[h], e + 2, 64) * xv2 + __shfl(w[h], e + 3, 64) * xv3;
      }
    }
    for (; e < deg; ++e) {
      int s0 = __shfl(s, e, 64);
      float xv0 = row_ptr(s0, ut, it)[lane];
#pragma unroll
      for (int h = 0; h < HC; ++h) acc[h] += __shfl(w[h], e, 64) * xv0;
    }
  } else {
    // ---- generic fallback (deg > 64): two streaming passes ----
    float sums[HC];
#pragma unroll
    for (int h = 0; h < HC; ++h) sums[h] = 0.f;
    for (int e = beg + lane; e < end; e += 64) {
      int s = srcs[e];
      float ev[HC];
      ld_e<HC>(e1s, s, hbase, ev);
#pragma unroll
      for (int h = 0; h < HC; ++h) {
        float x = ev[h] + edv[h];
        x = x > 0.f ? x : 0.2f * x;
        sums[h] += __expf(x);
      }
    }
#pragma unroll
    for (int h = 0; h < HC; ++h) {
#pragma unroll
      for (int off = 32; off; off >>= 1) sums[h] += __shfl_xor(sums[h], off, 64);
    }
    float inv[HC];
#pragma unroll
    for (int h = 0; h < HC; ++h) inv[h] = 1.f / (sums[h] + 1e-8f);
    for (int e = beg; e < end; ++e) {
      int s0 = srcs[e];
      float ev0[HC];
      ld_e<HC>(e1s, s0, hbase, ev0);
      float xv0 = row_ptr(s0, ut, it)[lane];
#pragma unroll
      for (int h = 0; h < HC; ++h) {
        float x0 = ev0[h] + edv[h];
        x0 = x0 > 0.f ? x0 : 0.2f * x0;
        acc[h] += __expf(x0) * inv[h] * xv0;
      }
    }
  }
#pragma unroll
  for (int h = 0; h < HC; ++h)
    aggX[(size_t)node * (HC * 64) + h * 64 + lane] = acc[h];
}

// ---------------- dense transform: h2 += elu(aggX_h @ W1_h) @ W2_h ----------------
// Row-major LDS tiles only (pad 68 keeps float4 alignment; all accesses at or
// near the b128 bandwidth floor — no transpose anywhere: the ELU intermediate
// is written row-major and re-read with the same pattern). Fused e2 on last.
template <int HC>
__global__ __launch_bounds__(256, 3) void trans_kernel(
    const float* __restrict__ aggX, const float* __restrict__ W1,
    const float* __restrict__ W2, const float* __restrict__ a2,
    int hbase, int last, float* __restrict__ h2,
    float* __restrict__ e2s, float* __restrict__ e2d) {
  __shared__ __align__(16) float xs[64][68];   // A rows (row-major, k contiguous)
  __shared__ __align__(16) float wsm[64][68];  // W rows
  const int t = threadIdx.x;
  const int rb = blockIdx.x;
  const int j = t & 15, i = t >> 4;
  const int row0 = rb * 64;

  float acc2[4][4];
#pragma unroll
  for (int r = 0; r < 4; ++r) { acc2[r][0] = 0.f; acc2[r][1] = 0.f; acc2[r][2] = 0.f; acc2[r][3] = 0.f; }
  if (hbase != 0) {
#pragma unroll
    for (int r = 0; r < 4; ++r) {
      int grow = row0 + i * 4 + r;
      if (grow < NUM_NODES) {
        float4 v = *(const float4*)(h2 + (size_t)grow * 64 + j * 4);
        acc2[r][0] = v.x; acc2[r][1] = v.y; acc2[r][2] = v.z; acc2[r][3] = v.w;
      }
    }
  }

#pragma unroll 1
  for (int h = 0; h < HC; ++h) {
    __syncthreads();  // previous head's GEMM2 reads complete
    // stage A tile (row-major) + W1 head slice
#pragma unroll
    for (int u = 0; u < 4; ++u) {
      int idx = t + u * 256, rw = idx >> 4, f4 = idx & 15;
      int grow = row0 + rw;
      float4 v = make_float4(0.f, 0.f, 0.f, 0.f);
      if (grow < NUM_NODES)
        v = *(const float4*)(aggX + (size_t)grow * (HC * 64) + h * 64 + f4 * 4);
      *(float4*)&xs[rw][f4 * 4] = v;
      *(float4*)&wsm[rw][f4 * 4] =
          *(const float4*)(W1 + (size_t)rw * 256 + (hbase + h) * 64 + f4 * 4);
    }
    __syncthreads();

    // GEMM1: t1[r][cc] = sum_k A[i4+r][k] * W1[k][j4+cc]
    float t1[4][4] = {{0.f,0.f,0.f,0.f},{0.f,0.f,0.f,0.f},{0.f,0.f,0.f,0.f},{0.f,0.f,0.f,0.f}};
#pragma unroll 2
    for (int k4 = 0; k4 < 16; ++k4) {
      float4 a0 = *(const float4*)&xs[i * 4 + 0][k4 * 4];
      float4 a1_ = *(const float4*)&xs[i * 4 + 1][k4 * 4];
      float4 a2_ = *(const float4*)&xs[i * 4 + 2][k4 * 4];
      float4 a3 = *(const float4*)&xs[i * 4 + 3][k4 * 4];
#pragma unroll
      for (int c = 0; c < 4; ++c) {
        float4 bv = *(const float4*)&wsm[k4 * 4 + c][j * 4];
        float av0 = (&a0.x)[c], av1 = (&a1_.x)[c], av2 = (&a2_.x)[c], av3 = (&a3.x)[c];
        t1[0][0] += av0 * bv.x; t1[0][1] += av0 * bv.y; t1[0][2] += av0 * bv.z; t1[0][3] += av0 * bv.w;
        t1[1][0] += av1 * bv.x; t1[1][1] += av1 * bv.y; t1[1][2] += av1 * bv.z; t1[1][3] += av1 * bv.w;
        t1[2][0] += av2 * bv.x; t1[2][1] += av2 * bv.y; t1[2][2] += av2 * bv.z; t1[2][3] += av2 * bv.w;
        t1[3][0] += av3 * bv.x; t1[3][1] += av3 * bv.y; t1[3][2] += av3 * bv.z; t1[3][3] += av3 * bv.w;
      }
    }
    __syncthreads();  // GEMM1 LDS reads complete before overwrite

    // ELU + write back row-major (same layout → GEMM2 reads like GEMM1; no transpose)
#pragma unroll
    for (int r = 0; r < 4; ++r) {
      float4 o;
      o.x = t1[r][0] > 0.f ? t1[r][0] : expm1f(t1[r][0]);
      o.y = t1[r][1] > 0.f ? t1[r][1] : expm1f(t1[r][1]);
      o.z = t1[r][2] > 0.f ? t1[r][2] : expm1f(t1[r][2]);
      o.w = t1[r][3] > 0.f ? t1[r][3] : expm1f(t1[r][3]);
      *(float4*)&xs[i * 4 + r][j * 4] = o;
    }
#pragma unroll
    for (int u = 0; u < 4; ++u) {
      int idx = t + u * 256, rw = idx >> 4, f4 = idx & 15;
      *(float4*)&wsm[rw][f4 * 4] =
          *(const float4*)(W2 + (size_t)((hbase + h) * 64 + rw) * 64 + f4 * 4);
    }
    __syncthreads();

    // GEMM2: acc2[r][cc] += sum_k elu[i4+r][k] * W2[k][j4+cc]
#pragma unroll 2
    for (int k4 = 0; k4 < 16; ++k4) {
      float4 a0 = *(const float4*)&xs[i * 4 + 0][k4 * 4];
      float4 a1_ = *(const float4*)&xs[i * 4 + 1][k4 * 4];
      float4 a2_ = *(const float4*)&xs[i * 4 + 2][k4 * 4];
      float4 a3 = *(const float4*)&xs[i * 4 + 3][k4 * 4];
#pragma unroll
      for (int c = 0; c < 4; ++c) {
        float4 bv = *(const float4*)&wsm[k4 * 4 + c][j * 4];
        float av0 = (&a0.x)[c], av1 = (&a1_.x)[c], av2 = (&a2_.x)[c], av3 = (&a3.x)[c];
        acc2[0][0] += av0 * bv.x; acc2[0][1] += av0 * bv.y; acc2[0][2] += av0 * bv.z; acc2[0][3] += av0 * bv.w;
        acc2[1][0] += av1 * bv.x; acc2[1][1] += av1 * bv.y; acc2[1][2] += av1 * bv.z; acc2[1][3] += av1 * bv.w;
        acc2[2][0] += av2 * bv.x; acc2[2][1] += av2 * bv.y; acc2[2][2] += av2 * bv.z; acc2[2][3] += av2 * bv.w;
        acc2[3][0] += av3 * bv.x; acc2[3][1] += av3 * bv.y; acc2[3][2] += av3 * bv.z; acc2[3][3] += av3 * bv.w;
      }
    }
  }

  // store h2 tile
#pragma unroll
  for (int r = 0; r < 4; ++r) {
    int grow = row0 + i * 4 + r;
    if (grow < NUM_NODES) {
      float4 o = make_float4(acc2[r][0], acc2[r][1], acc2[r][2], acc2[r][3]);
      *(float4*)(h2 + (size_t)grow * 64 + j * 4) = o;
    }
  }

  // fused e2 projections once h2 is complete
  if (last) {
    const float4 alv = *(const float4*)(a2 + j * 4);
    const float4 arv = *(const float4*)(a2 + 64 + j * 4);
#pragma unroll
    for (int r = 0; r < 4; ++r) {
      float ps = acc2[r][0] * alv.x + acc2[r][1] * alv.y + acc2[r][2] * alv.z + acc2[r][3] * alv.w;
      float pd = acc2[r][0] * arv.x + acc2[r][1] * arv.y + acc2[r][2] * arv.z + acc2[r][3] * arv.w;
#pragma unroll
      for (int off = 1; off < 16; off <<= 1) {
        ps += __shfl_xor(ps, off, 64);
        pd += __shfl_xor(pd, off, 64);
      }
      if (j == 0) {
        int grow = row0 + i * 4 + r;
        if (grow < NUM_NODES) { e2s[grow] = ps; e2d[grow] = pd; }
      }
    }
  }
}

// ---------------- layer-2 aggregation + residual (flagged nodes only) ----------------
__global__ __launch_bounds__(256) void agg2_kernel(
    const int* __restrict__ offsets, const int* __restrict__ srcs,
    const float* __restrict__ e2s, const float* __restrict__ e2d,
    const int* __restrict__ flags, const float* __restrict__ h2,
    const float* __restrict__ ut, const float* __restrict__ it,
    float* __restrict__ hfin) {
  int wid = threadIdx.x >> 6, lane = threadIdx.x & 63;
  int node = blockIdx.x * 4 + wid;
  if (node >= NUM_NODES) return;
  if (!flags[node]) return;  // output never read for this node
  int beg = offsets[node], end = offsets[node + 1];
  int deg = end - beg;
  float edv = e2d[node];
  float acc = 0.f;

  if (deg <= 64) {
    int s = 0;
    float w = 0.f;
    if (lane < deg) {
      s = srcs[beg + lane];
      float x = e2s[s] + edv;
      x = x > 0.f ? x : 0.2f * x;
      w = __expf(x);
    }
    float sum = w;
#pragma unroll
    for (int off = 32; off; off >>= 1) sum += __shfl_xor(sum, off, 64);
    w *= 1.f / (sum + 1e-8f);
    int e = 0;
    for (; e + 4 <= deg; e += 4) {
      int s0 = __shfl(s, e, 64), s1 = __shfl(s, e + 1, 64);
      int s2 = __shfl(s, e + 2, 64), s3 = __shfl(s, e + 3, 64);
      float hv0 = h2[(size_t)s0 * 64 + lane];
      float hv1 = h2[(size_t)s1 * 64 + lane];
      float hv2 = h2[(size_t)s2 * 64 + lane];
      float hv3 = h2[(size_t)s3 * 64 + lane];
      acc += __shfl(w, e, 64) * hv0 + __shfl(w, e + 1, 64) * hv1 +
             __shfl(w, e + 2, 64) * hv2 + __shfl(w, e + 3, 64) * hv3;
    }
    for (; e < deg; ++e) {
      int s0 = __shfl(s, e, 64);
      acc += __shfl(w, e, 64) * h2[(size_t)s0 * 64 + lane];
    }
  } else {
    float psum = 0.f;
    for (int e = beg + lane; e < end; e += 64) {
      int s = srcs[e];
      float x = e2s[s] + edv;
      x = x > 0.f ? x : 0.2f * x;
      psum += __expf(x);
    }
#pragma unroll
    for (int off = 32; off; off >>= 1) psum += __shfl_xor(psum, off, 64);
    float inv = 1.f / (psum + 1e-8f);
    for (int e = beg; e < end; ++e) {
      int s0 = srcs[e];
      float x0 = e2s[s0] + edv;
      x0 = x0 > 0.f ? x0 : 0.2f * x0;
      acc += __expf(x0) * inv * h2[(size_t)s0 * 64 + lane];
    }
  }
  float res = (node < NUM_USERS) ? ut[(size_t)node * 64 + lane]
                                 : it[(size_t)(node - NUM_USERS) * 64 + lane];
  hfin[(size_t)node * 64 + lane] = acc + res;
}

// ---------------- final batched dot ----------------
__global__ __launch_bounds__(256) void final_kernel(
    const float* __restrict__ hf, const int* __restrict__ uid,
    const int* __restrict__ iid, float* __restrict__ out) {
  int wid = threadIdx.x >> 6, lane = threadIdx.x & 63;
  int idx = blockIdx.x * 4 + wid;
  if (idx >= BATCH) return;
  int u = uid[idx], v = iid[idx];
  float a = hf[(size_t)u * 64 + lane];
  float b = hf[(size_t)(NUM_USERS + v) * 64 + lane];
  float p = a * b;
#pragma unroll
  for (int off = 32; off; off >>= 1) p += __shfl_xor(p, off, 64);
  if (lane == 0) out[idx] = p;
}

extern "C" void kernel_launch(void* const* d_in, const int* in_sizes, int n_in,
                              void* d_out, int out_size, void* d_ws, size_t ws_size,
                              hipStream_t stream) {
  const float* user_table = (const float*)d_in[0];
  const float* item_table = (const float*)d_in[1];
  const float* W1 = (const float*)d_in[2];
  const float* a1 = (const float*)d_in[3];
  const float* W2 = (const float*)d_in[4];
  const float* a2 = (const float*)d_in[5];
  const int* edge_index = (const int*)d_in[6];
  const int* user_ids = (const int*)d_in[7];
  const int* item_ids = (const int*)d_in[8];
  float* out = (float*)d_out;

  const int* src = edge_index;
  const int* dst = edge_index + NUM_EDGES;

  // ---- workspace layout (elements), aggX sized by ws_size ----
  float* ws = (float*)d_ws;
  size_t off = 0;
  auto falloc = [&](size_t n) { float* p = ws + off; off += n; return p; };
  float* h2  = falloc((size_t)NUM_NODES * 64);
  float* e1s = falloc((size_t)NUM_NODES * 4);
  float* e1d = falloc((size_t)NUM_NODES * 4);
  float* e2s = falloc(NUM_NODES);
  float* e2d = falloc(NUM_NODES);
  float* w1a = falloc(256);
  float* w1b = falloc(256);
  int* count   = (int*)falloc(NUM_NODES);
  int* offsets = (int*)falloc(NUM_NODES + 1);
  int* cursor  = (int*)falloc(NUM_NODES);
  int* srcs    = (int*)falloc(NUM_EDGES);
  int* flags   = (int*)falloc(NUM_NODES);
  int* bsum    = (int*)falloc(NB_SCAN);
  int* bpre    = (int*)falloc(NB_SCAN);
  off = (off + 3) & ~(size_t)3;  // 16B-align aggX for float4 access
  float* aggX = ws + off;
  size_t availElems = (ws_size / 4 > off) ? (ws_size / 4 - off) : 0;

  // head-chunk size: 4 heads in one edge pass if aggX fits, else 2, else 1
  int HC = 1;
  if (availElems >= (size_t)NUM_NODES * 256) HC = 4;
  else if (availElems >= (size_t)NUM_NODES * 128) HC = 2;
  float* hfin = aggX;  // alias: aggX dead after last trans pass

  const int eb = (NUM_EDGES + 255) / 256;
  const int nb4 = (NUM_NODES + 3) / 4;
  const int nb64 = (NUM_NODES + 63) / 64;

  zero_kernel<<<(NUM_NODES + 255) / 256, 256, 0, stream>>>(count, flags);
  flag_kernel<<<(BATCH + 255) / 256, 256, 0, stream>>>(user_ids, item_ids, flags);
  hist_kernel<<<eb, 256, 0, stream>>>(dst, count);
  blocksum_kernel<<<NB_SCAN, 256, 0, stream>>>(count, bsum);
  scanb_kernel<<<1, 1024, 0, stream>>>(bsum, bpre, offsets);
  scanf_kernel<<<NB_SCAN, 256, 0, stream>>>(count, bpre, offsets, cursor);
  scatter_kernel<<<eb, 256, 0, stream>>>(src, dst, cursor, srcs);

  proj1_kernel<<<1, 256, 0, stream>>>(W1, a1, w1a, w1b);
  e1_kernel<<<nb4, 256, 0, stream>>>(user_table, item_table, w1a, w1b, e1s, e1d);

  for (int hbase = 0; hbase < 4; hbase += HC) {
    int last = (hbase + HC == 4) ? 1 : 0;
    switch (HC) {
      case 4:
        aggX_kernel<4><<<nb4, 256, 0, stream>>>(offsets, srcs, e1s, e1d,
                                                user_table, item_table, hbase, aggX);
        trans_kernel<4><<<nb64, 256, 0, stream>>>(aggX, W1, W2, a2, hbase, last,
                                                  h2, e2s, e2d);
        break;
      case 2:
        aggX_kernel<2><<<nb4, 256, 0, stream>>>(offsets, srcs, e1s, e1d,
                                                user_table, item_table, hbase, aggX);
        trans_kernel<2><<<nb64, 256, 0, stream>>>(aggX, W1, W2, a2, hbase, last,
                                                  h2, e2s, e2d);
        break;
      default:
        aggX_kernel<1><<<nb4, 256, 0, stream>>>(offsets, srcs, e1s, e1d,
                                                user_table, item_table, hbase, aggX);
        trans_kernel<1><<<nb64, 256, 0, stream>>>(aggX, W1, W2, a2, hbase, last,
                                                  h2, e2s, e2d);
        break;
    }
  }

  agg2_kernel<<<nb4, 256, 0, stream>>>(offsets, srcs, e2s, e2d, flags,
                                       h2, user_table, item_table, hfin);
  final_kernel<<<(BATCH + 3) / 4, 256, 0, stream>>>(hfin, user_ids, item_ids, out);
}